// Round 7
// baseline (883.647 us; speedup 1.0000x reference)
//
#include <hip/hip_runtime.h>
#include <math.h>

// Model dims
#define D_MODEL 256
#define NTOK    8192      // B*S
#define SEQ     512
#define NB      16
#define NH      8
#define DHEAD   32
#define NE      8
#define EHID    1024
#define CSTRIDE 32        // counts[] cacheline stride (ints)

typedef __attribute__((ext_vector_type(8))) short short8;
typedef __attribute__((ext_vector_type(4))) float floatx4;
typedef unsigned short ushort_t;

__device__ __forceinline__ ushort_t bf16r(float f) {
    unsigned int u = __float_as_uint(f);
    u += 0x7fffu + ((u >> 16) & 1u);     // round-to-nearest-even
    return (ushort_t)(u >> 16);
}
__device__ __forceinline__ float bf2f(ushort_t b) {
    return __uint_as_float(((unsigned)b) << 16);
}

// ---------------------------------------------------------------------------
// Fused fp32 -> bf16 conversion of ALL weights (both layers), one launch.
// ---------------------------------------------------------------------------
__global__ __launch_bounds__(256) void wconv_all(
    const float* __restrict__ in_proj_w, const float* __restrict__ out_proj_w,
    const float* __restrict__ w1, const float* __restrict__ w2,
    ushort_t* __restrict__ wball)
{
    const int g = blockIdx.x * 256 + threadIdx.x;   // quad index
    const float* src; ushort_t* dst; int lo;
    if (g < 98304)        { src = in_proj_w;  dst = wball;           lo = g; }
    else if (g < 131072)  { src = out_proj_w; dst = wball + 393216;  lo = g - 98304; }
    else if (g < 1179648) { src = w1;         dst = wball + 524288;  lo = g - 131072; }
    else                  { src = w2;         dst = wball + 4718592; lo = g - 1179648; }
    float4 v = *(const float4*)(src + (size_t)lo * 4);
    ushort_t o[4] = { bf16r(v.x), bf16r(v.y), bf16r(v.z), bf16r(v.w) };
    *(uint2*)(dst + (size_t)lo * 4) = *(uint2*)o;
}

// ---------------------------------------------------------------------------
// Embedding + positional encoding + pad mask. Writes h (fp32) and hb (bf16).
// ---------------------------------------------------------------------------
__global__ __launch_bounds__(256) void embed_kernel(
    const int* __restrict__ x, const float* __restrict__ emb,
    float* __restrict__ h, ushort_t* __restrict__ hb, int* __restrict__ pad)
{
    __shared__ float wred[4];
    const int n = blockIdx.x;
    const int d = threadIdx.x;
    const int wave = d >> 6;
    const int s = n & (SEQ - 1);
    const int tok = x[n];
    float v = emb[tok * D_MODEL + d] * 16.0f;   // sqrt(256)
    const int j = d >> 1;
    const float c = -9.210340371976184f / 256.0f;
    const float div = expf((float)(2 * j) * c);
    const float ang = (float)s * div;
    v += (d & 1) ? cosf(ang) : sinf(ang);
    h[n * D_MODEL + d] = v;
    hb[n * D_MODEL + d] = bf16r(v);
    float sm = v;
    for (int o = 1; o < 64; o <<= 1) sm += __shfl_xor(sm, o);
    if ((d & 63) == 0) wred[wave] = sm;
    __syncthreads();
    if (d == 0) pad[n] = ((wred[0] + wred[1] + wred[2] + wred[3]) == 0.0f) ? 1 : 0;
}

// ---------------------------------------------------------------------------
// 128x128 bf16 MFMA GEMM: C[M,N] = A[M,K] @ B[N,K]^T + bias[N]
// BK=64, 256 threads = 4 waves in 2x2, each wave a 64x64 output tile
// (16 floatx4 acc). __launch_bounds__(256,2) -> VGPR cap 256, no spill
// (round-5 lesson: bare launch_bounds(256) let the heuristic alloc 48 VGPR
// and spill the K-loop to scratch).
// Segmented (MoE) mode when counts != nullptr (padded stride CSTRIDE).
// ---------------------------------------------------------------------------
#define GF_RELU    1
#define GF_OUTBF16 2
#define GF_GATHER  4
#define GF_SCATTER 8

__global__ __launch_bounds__(256, 2) void gemm128(
    const ushort_t* __restrict__ A, const ushort_t* __restrict__ Bw,
    const float* __restrict__ bias, void* __restrict__ Cout,
    int M, int N, int K,
    const int* __restrict__ counts,
    const int* __restrict__ perm, const float* __restrict__ topw,
    int flags)
{
    __shared__ ushort_t As[128][72];   // 128 rows x (64 + 8 pad) bf16 = 18 KB
    __shared__ ushort_t Bs[128][72];
    const int e = blockIdx.z;
    int cnt, off = 0;
    if (counts) {
        cnt = counts[e * CSTRIDE];
        if ((int)blockIdx.y * 128 >= cnt) return;
        for (int i = 0; i < e; i++) off += counts[i * CSTRIDE];
    } else { cnt = M; }
    const ushort_t* Bp = Bw + (size_t)e * N * K;
    const float* bp = bias + (size_t)e * N;
    const int m0 = blockIdx.y * 128, n0 = blockIdx.x * 128;
    const int tid = threadIdx.x;
    const int srow = tid >> 3;          // 0..31
    const int kc0 = (tid & 7) * 8;      // 0..56
    // A row bases (gather-aware), fixed across K iterations
    size_t arow[4];
#pragma unroll
    for (int i = 0; i < 4; i++) {
        const int r = m0 + i * 32 + srow;
        const bool v = r < cnt;
        if (flags & GF_GATHER) arow[i] = (size_t)perm[off + (v ? r : 0)];
        else                   arow[i] = (size_t)(off + (v ? r : 0));
    }
    const int lane = tid & 63, wave = tid >> 6;
    const int wm = (wave & 1) * 64, wn = (wave >> 1) * 64;
    const int fr = lane & 15, fk = (lane >> 4) * 8;
    floatx4 acc[4][4];
#pragma unroll
    for (int i = 0; i < 4; i++)
#pragma unroll
        for (int jj = 0; jj < 4; jj++) acc[i][jj] = (floatx4){0.f, 0.f, 0.f, 0.f};

    for (int k0 = 0; k0 < K; k0 += 64) {
        uint4 av[4], bv[4];
#pragma unroll
        for (int i = 0; i < 4; i++)
            av[i] = *(const uint4*)(A + arow[i] * K + k0 + kc0);
#pragma unroll
        for (int i = 0; i < 4; i++)
            bv[i] = *(const uint4*)(Bp + (size_t)(n0 + i * 32 + srow) * K + k0 + kc0);
        __syncthreads();
#pragma unroll
        for (int i = 0; i < 4; i++) *(uint4*)&As[i * 32 + srow][kc0] = av[i];
#pragma unroll
        for (int i = 0; i < 4; i++) *(uint4*)&Bs[i * 32 + srow][kc0] = bv[i];
        __syncthreads();
#pragma unroll
        for (int ks = 0; ks < 2; ks++) {
            const int ko = ks * 32 + fk;
            short8 fa[4], fb[4];
#pragma unroll
            for (int m = 0; m < 4; m++) fa[m] = *(const short8*)&As[wm + m * 16 + fr][ko];
#pragma unroll
            for (int n = 0; n < 4; n++) fb[n] = *(const short8*)&Bs[wn + n * 16 + fr][ko];
#pragma unroll
            for (int m = 0; m < 4; m++)
#pragma unroll
                for (int n = 0; n < 4; n++)
                    acc[m][n] = __builtin_amdgcn_mfma_f32_16x16x32_bf16(fa[m], fb[n], acc[m][n], 0, 0, 0);
        }
    }
    const int crow0 = (lane >> 4) * 4;
    const int ccol = lane & 15;
#pragma unroll
    for (int m = 0; m < 4; m++) {
#pragma unroll
        for (int n = 0; n < 4; n++) {
            const int gcol = n0 + wn + n * 16 + ccol;
            const float bsv = bp[gcol];
#pragma unroll
            for (int r = 0; r < 4; r++) {
                const int grow = m0 + wm + m * 16 + crow0 + r;
                if (grow >= cnt) continue;
                float v = acc[m][n][r] + bsv;
                if (flags & GF_RELU) v = fmaxf(v, 0.f);
                if (flags & GF_SCATTER) {
                    const int tok = perm[off + grow];
                    ((float*)Cout)[(size_t)tok * N + gcol] = v * topw[tok];
                } else if (flags & GF_OUTBF16) {
                    ((ushort_t*)Cout)[(size_t)(off + grow) * N + gcol] = bf16r(v);
                } else {
                    ((float*)Cout)[(size_t)(off + grow) * N + gcol] = v;
                }
            }
        }
    }
}

// ---------------------------------------------------------------------------
// MFMA flash-style attention (verified round 3).
// ---------------------------------------------------------------------------
__global__ __launch_bounds__(256) void attn_kernel(
    const ushort_t* __restrict__ qkvb, const int* __restrict__ pad,
    ushort_t* __restrict__ ctxb)
{
    __shared__ ushort_t Kt[64 * 40];
    __shared__ ushort_t Vt[32 * 72];
    __shared__ ushort_t Ps[64 * 72];
    __shared__ float padf[512];
    const int tid = threadIdx.x;
    const int lane = tid & 63;
    const int wave = tid >> 6;
    const int quad = lane >> 4;
    const int l16  = lane & 15;
    const int bid = blockIdx.x;
    const int qt = bid & 7;
    const int hh = (bid >> 3) & 7;
    const int b = bid >> 6;
    const int q0 = wave * 16;

    padf[tid]       = (float)pad[b * SEQ + tid];
    padf[tid + 256] = (float)pad[b * SEQ + 256 + tid];

    short8 qfrag = *(const short8*)(qkvb +
        (size_t)(b * SEQ + qt * 64 + q0 + l16) * 768 + hh * 32 + quad * 8);

    const int skey = tid >> 2;
    const int schunk = (tid & 3) * 8;

    floatx4 o0 = {0.f,0.f,0.f,0.f}, o1 = {0.f,0.f,0.f,0.f};
    float lsum[4] = {0.f, 0.f, 0.f, 0.f};
    const float scale = 0.17677669529663687f;

    for (int t = 0; t < 8; t++) {
        const int kbase = b * SEQ + t * 64;
        __syncthreads();
        uint4 kv = *(const uint4*)(qkvb + (size_t)(kbase + skey) * 768 + 256 + hh * 32 + schunk);
        *(uint4*)&Kt[skey * 40 + schunk] = kv;
        uint4 vv = *(const uint4*)(qkvb + (size_t)(kbase + skey) * 768 + 512 + hh * 32 + schunk);
        ushort_t vs[8]; *(uint4*)vs = vv;
#pragma unroll
        for (int j = 0; j < 8; j++) {
            const int d = schunk + j;
            Vt[d * 72 + (skey ^ ((d >> 3) << 3))] = vs[j];
        }
        __syncthreads();
        floatx4 sfr[4];
#pragma unroll
        for (int fn = 0; fn < 4; fn++) {
            short8 kf = *(const short8*)&Kt[(fn * 16 + l16) * 40 + quad * 8];
            sfr[fn] = __builtin_amdgcn_mfma_f32_16x16x32_bf16(
                qfrag, kf, (floatx4){0.f,0.f,0.f,0.f}, 0, 0, 0);
        }
#pragma unroll
        for (int fn = 0; fn < 4; fn++) {
            const int keyl = fn * 16 + l16;
            const float pv = padf[t * 64 + keyl];
#pragma unroll
            for (int r = 0; r < 4; r++) {
                float p = (pv != 0.f) ? 0.f : __expf(sfr[fn][r] * scale);
                ushort_t pb = bf16r(p);
                lsum[r] += bf2f(pb);
                Ps[(q0 + quad * 4 + r) * 72 + keyl] = pb;
            }
        }
#pragma unroll
        for (int kc = 0; kc < 2; kc++) {
            short8 pf = *(const short8*)&Ps[(q0 + l16) * 72 + kc * 32 + quad * 8];
            {
                const int d = l16;
                short8 vf = *(const short8*)&Vt[d * 72 + ((kc * 32 + quad * 8) ^ ((d >> 3) << 3))];
                o0 = __builtin_amdgcn_mfma_f32_16x16x32_bf16(pf, vf, o0, 0, 0, 0);
            }
            {
                const int d = 16 + l16;
                short8 vf = *(const short8*)&Vt[d * 72 + ((kc * 32 + quad * 8) ^ ((d >> 3) << 3))];
                o1 = __builtin_amdgcn_mfma_f32_16x16x32_bf16(pf, vf, o1, 0, 0, 0);
            }
        }
    }
#pragma unroll
    for (int r = 0; r < 4; r++) {
        float v = lsum[r];
        v += __shfl_xor(v, 1); v += __shfl_xor(v, 2);
        v += __shfl_xor(v, 4); v += __shfl_xor(v, 8);
        lsum[r] = 1.f / v;
    }
    const int nq = b * SEQ + qt * 64 + q0 + quad * 4;
#pragma unroll
    for (int r = 0; r < 4; r++) {
        ushort_t* outp = ctxb + (size_t)(nq + r) * 256 + hh * 32;
        outp[l16]      = bf16r(o0[r] * lsum[r]);
        outp[16 + l16] = bf16r(o1[r] * lsum[r]);
    }
}

// ---------------------------------------------------------------------------
// Residual add + LayerNorm (in place into h, plus bf16 copy hb).
// ---------------------------------------------------------------------------
__global__ __launch_bounds__(256) void add_ln(
    float* __restrict__ h, const float* __restrict__ add,
    const float* __restrict__ g, const float* __restrict__ b,
    ushort_t* __restrict__ hb)
{
    __shared__ float wred[8];
    const int n = blockIdx.x;
    const int d = threadIdx.x;
    const int wave = d >> 6;
    const float v = h[n * D_MODEL + d] + add[n * D_MODEL + d];
    float s = v;
    for (int o = 1; o < 64; o <<= 1) s += __shfl_xor(s, o);
    if ((d & 63) == 0) wred[wave] = s;
    __syncthreads();
    const float mu = (wred[0] + wred[1] + wred[2] + wred[3]) * (1.0f / 256.0f);
    const float c = v - mu;
    float cs = c * c;
    for (int o = 1; o < 64; o <<= 1) cs += __shfl_xor(cs, o);
    if ((d & 63) == 0) wred[4 + wave] = cs;
    __syncthreads();
    const float var = (wred[4] + wred[5] + wred[6] + wred[7]) * (1.0f / 256.0f);
    const float o = c * rsqrtf(var + 1e-5f) * g[d] + b[d];
    h[n * D_MODEL + d] = o;
    hb[n * D_MODEL + d] = bf16r(o);
}

// ---------------------------------------------------------------------------
// Gate v2 (verified round 4): 128 tokens/block, LDS histogram, 8 padded
// global atomics per block.
// ---------------------------------------------------------------------------
__global__ __launch_bounds__(256) void gate_kernel(
    const float* __restrict__ h, const float* __restrict__ gw,
    const float* __restrict__ gb, int* __restrict__ top_idx,
    float* __restrict__ top_w, int* __restrict__ pos, int* __restrict__ counts)
{
    __shared__ int lidx[128];
    __shared__ int lpos[128];
    __shared__ int hist[NE];
    __shared__ int base[NE];
    const int wave = threadIdx.x >> 6;
    const int lane = threadIdx.x & 63;
    const int t0 = blockIdx.x * 128 + wave * 32;
    float4 gwr[NE];
#pragma unroll
    for (int e = 0; e < NE; e++)
        gwr[e] = *(const float4*)&gw[e * D_MODEL + lane * 4];
    float gbr[NE];
#pragma unroll
    for (int e = 0; e < NE; e++) gbr[e] = gb[e];

    for (int i = 0; i < 32; i++) {
        const int n = t0 + i;
        float4 hv = *(const float4*)&h[(size_t)n * D_MODEL + lane * 4];
        float lg[NE];
#pragma unroll
        for (int e = 0; e < NE; e++)
            lg[e] = hv.x * gwr[e].x + hv.y * gwr[e].y + hv.z * gwr[e].z + hv.w * gwr[e].w;
#pragma unroll
        for (int e = 0; e < NE; e++) {
            float v = lg[e];
            for (int o = 1; o < 64; o <<= 1) v += __shfl_xor(v, o);
            lg[e] = v;
        }
        if (lane == 0) {
            float best = -1e30f; int bi = 0;
#pragma unroll
            for (int e = 0; e < NE; e++) {
                lg[e] += gbr[e];
                if (lg[e] > best) { best = lg[e]; bi = e; }
            }
            float ssum = 0.0f;
#pragma unroll
            for (int e = 0; e < NE; e++) ssum += __expf(lg[e] - best);
            top_idx[n] = bi;
            top_w[n] = 1.0f / ssum;
            lidx[wave * 32 + i] = bi;
        }
    }
    __syncthreads();
    if (threadIdx.x < NE) hist[threadIdx.x] = 0;
    __syncthreads();
    if (threadIdx.x < 128)
        lpos[threadIdx.x] = atomicAdd(&hist[lidx[threadIdx.x]], 1);
    __syncthreads();
    if (threadIdx.x < NE)
        base[threadIdx.x] = atomicAdd(&counts[threadIdx.x * CSTRIDE], hist[threadIdx.x]);
    __syncthreads();
    if (threadIdx.x < 128)
        pos[blockIdx.x * 128 + threadIdx.x] = base[lidx[threadIdx.x]] + lpos[threadIdx.x];
}

__global__ __launch_bounds__(256) void scatter_perm(
    const int* __restrict__ top_idx, const int* __restrict__ pos,
    const int* __restrict__ counts, int* __restrict__ perm)
{
    __shared__ int offs_s[NE];
    if (threadIdx.x < NE) {
        int a = 0;
        for (int i = 0; i < (int)threadIdx.x; i++) a += counts[i * CSTRIDE];
        offs_s[threadIdx.x] = a;
    }
    __syncthreads();
    const int n = blockIdx.x * 256 + threadIdx.x;
    if (n < NTOK) perm[offs_s[top_idx[n]] + pos[n]] = n;
}

// ---------------------------------------------------------------------------
// Masked mean pool, stage 1: 16x16 blocks, partial sums via atomics.
// ---------------------------------------------------------------------------
__global__ __launch_bounds__(256) void pool1(
    const float* __restrict__ h, const int* __restrict__ pad,
    float* __restrict__ pooled, float* __restrict__ cntb)
{
    const int b = blockIdx.x, c = blockIdx.y, d = threadIdx.x;
    float s = 0.0f; int cnt = 0;
    for (int i = 0; i < 32; i++) {
        const int idx = b * SEQ + c * 32 + i;
        if (!pad[idx]) { s += h[(size_t)idx * D_MODEL + d]; cnt++; }
    }
    atomicAdd(&pooled[b * D_MODEL + d], s);
    if (d == 0) atomicAdd(&cntb[b], (float)cnt);
}

__global__ __launch_bounds__(128) void cls_kernel(
    const float* __restrict__ pooled, const float* __restrict__ cntb,
    const float* __restrict__ fc1w, const float* __restrict__ fc1b,
    const float* __restrict__ fc2w, const float* __restrict__ fc2b,
    float* __restrict__ out)
{
    __shared__ float zs[128];
    const int b = blockIdx.x;
    const int j = threadIdx.x;
    const float invc = 1.0f / fmaxf(cntb[b], 1.0f);
    float s = 0.0f;
    for (int d = 0; d < D_MODEL; d++) s += pooled[b * D_MODEL + d] * fc1w[j * D_MODEL + d];
    zs[j] = fmaxf(s * invc + fc1b[j], 0.0f);
    __syncthreads();
    if (j < 2) {
        float o = fc2b[j];
        for (int i = 0; i < 128; i++) o += zs[i] * fc2w[j * 128 + i];
        out[b * 2 + j] = o;
    }
}

// ---------------------------------------------------------------------------
extern "C" void kernel_launch(void* const* d_in, const int* in_sizes, int n_in,
                              void* d_out, int out_size, void* d_ws, size_t ws_size,
                              hipStream_t stream)
{
    const int*   x          = (const int*)d_in[0];
    const float* emb        = (const float*)d_in[1];
    const float* in_proj_w  = (const float*)d_in[2];
    const float* in_proj_b  = (const float*)d_in[3];
    const float* out_proj_w = (const float*)d_in[4];
    const float* out_proj_b = (const float*)d_in[5];
    const float* ln1_g      = (const float*)d_in[6];
    const float* ln1_b      = (const float*)d_in[7];
    const float* ln2_g      = (const float*)d_in[8];
    const float* ln2_b      = (const float*)d_in[9];
    const float* gate_w     = (const float*)d_in[10];
    const float* gate_b     = (const float*)d_in[11];
    const float* w1         = (const float*)d_in[12];
    const float* b1         = (const float*)d_in[13];
    const float* w2         = (const float*)d_in[14];
    const float* b2         = (const float*)d_in[15];
    const float* fc1_w      = (const float*)d_in[16];
    const float* fc1_b      = (const float*)d_in[17];
    const float* fc2_w      = (const float*)d_in[18];
    const float* fc2_b      = (const float*)d_in[19];
    float* out = (float*)d_out;

    // workspace layout (float slots)
    float* ws = (float*)d_ws;
    float*    h      = ws;                          // 2,097,152 f
    float*    tmp    = ws + 2097152;                // 2,097,152 f
    ushort_t* qkvb   = (ushort_t*)(ws + 4194304);   // 8192*768 bf16
    ushort_t* ctxb   = (ushort_t*)(ws + 7340032);   // 8192*256 bf16
    ushort_t* ehb    = (ushort_t*)(ws + 4194304);   // 8192*1024 bf16 aliases qkvb+ctxb
    ushort_t* hb     = (ushort_t*)(ws + 8388608);   // 8192*256 bf16
    float*    top_w  = ws + 10485760;               // 8192
    float*    pooled = ws + 10493952;               // 4096
    float*    cntb   = ws + 10498048;               // 16
    int* ipart   = (int*)(ws + 10498064);
    int* pad     = ipart;              // 8192
    int* top_idx = ipart + 8192;
    int* pos     = ipart + 16384;
    int* perm    = ipart + 24576;
    int* counts  = ipart + 32768;      // NE*CSTRIDE
    ushort_t* wball = (ushort_t*)(ws + 10531088);   // 8,912,896 bf16 (17.8 MB)

    // all-weight bf16 conversion, one launch
    wconv_all<<<8704, 256, 0, stream>>>(in_proj_w, out_proj_w, w1, w2, wball);
    embed_kernel<<<NTOK, 256, 0, stream>>>(x, emb, h, hb, pad);
    hipMemsetAsync(pooled, 0, (NB * D_MODEL + NB) * sizeof(float), stream);

    for (int l = 0; l < 2; l++) {
        const ushort_t* inb_l  = wball + (size_t)l * 196608;
        const ushort_t* outb_l = wball + 393216 + (size_t)l * 65536;
        const ushort_t* w1b_l  = wball + 524288 + (size_t)l * 2097152;
        const ushort_t* w2b_l  = wball + 4718592 + (size_t)l * 2097152;

        // --- qkv projection: [8192,256] x [768,256]^T -> qkvb (bf16) ---
        gemm128<<<dim3(768 / 128, NTOK / 128, 1), 256, 0, stream>>>(
            hb, inb_l, in_proj_b + l * 768, qkvb, NTOK, 768, 256,
            nullptr, nullptr, nullptr, GF_OUTBF16);
        // --- attention (MFMA flash) -> ctxb ---
        attn_kernel<<<NB * NH * (SEQ / 64), 256, 0, stream>>>(qkvb, pad, ctxb);
        // --- output projection -> tmp (fp32) ---
        gemm128<<<dim3(256 / 128, NTOK / 128, 1), 256, 0, stream>>>(
            ctxb, outb_l, out_proj_b + l * 256, tmp, NTOK, 256, 256,
            nullptr, nullptr, nullptr, 0);
        add_ln<<<NTOK, 256, 0, stream>>>(h, tmp, ln1_g + l * 256, ln1_b + l * 256, hb);
        // --- MoE routing ---
        hipMemsetAsync(counts, 0, NE * CSTRIDE * sizeof(int), stream);
        gate_kernel<<<NTOK / 128, 256, 0, stream>>>(
            h, gate_w + l * NE * 256, gate_b + l * NE, top_idx, top_w, pos, counts);
        scatter_perm<<<NTOK / 256, 256, 0, stream>>>(top_idx, pos, counts, perm);
        // --- MoE expert GEMMs (routed expert only) ---
        gemm128<<<dim3(EHID / 128, NTOK / 128, NE), 256, 0, stream>>>(
            hb, w1b_l, b1 + l * NE * EHID, ehb, 0, EHID, 256,
            counts, perm, nullptr, GF_GATHER | GF_RELU | GF_OUTBF16);
        gemm128<<<dim3(D_MODEL / 128, NTOK / 128, NE), 256, 0, stream>>>(
            ehb, w2b_l, b2 + l * NE * 256, tmp, 0, D_MODEL, 1024,
            counts, perm, top_w, GF_SCATTER);
        add_ln<<<NTOK, 256, 0, stream>>>(h, tmp, ln2_g + l * 256, ln2_b + l * 256, hb);
    }

    pool1<<<dim3(NB, 16), 256, 0, stream>>>(h, pad, pooled, cntb);
    cls_kernel<<<NB, 128, 0, stream>>>(pooled, cntb, fc1_w, fc1_b, fc2_w, fc2_b, out);
}

// Round 8
// 552.793 us; speedup vs baseline: 1.5985x; 1.5985x over previous
//
#include <hip/hip_runtime.h>
#include <math.h>

// Model dims
#define D_MODEL 256
#define NTOK    8192      // B*S
#define SEQ     512
#define NB      16
#define NH      8
#define DHEAD   32
#define NE      8
#define EHID    1024
#define CSTRIDE 32        // counts[] cacheline stride (ints)

typedef __attribute__((ext_vector_type(8))) short short8;
typedef __attribute__((ext_vector_type(4))) float floatx4;
typedef unsigned short ushort_t;

__device__ __forceinline__ ushort_t bf16r(float f) {
    unsigned int u = __float_as_uint(f);
    u += 0x7fffu + ((u >> 16) & 1u);     // round-to-nearest-even
    return (ushort_t)(u >> 16);
}
__device__ __forceinline__ float bf2f(ushort_t b) {
    return __uint_as_float(((unsigned)b) << 16);
}

// async global -> LDS DMA, 16 B per lane; LDS dest = wave-uniform base + lane*16
#define GLD16(gsrc, ldst) \
    __builtin_amdgcn_global_load_lds( \
        (const __attribute__((address_space(1))) void*)(gsrc), \
        (__attribute__((address_space(3))) void*)(ldst), 16, 0, 0)

// ---------------------------------------------------------------------------
// Fused fp32 -> bf16 conversion of ALL weights (both layers), one launch.
// ---------------------------------------------------------------------------
__global__ __launch_bounds__(256) void wconv_all(
    const float* __restrict__ in_proj_w, const float* __restrict__ out_proj_w,
    const float* __restrict__ w1, const float* __restrict__ w2,
    ushort_t* __restrict__ wball)
{
    const int g = blockIdx.x * 256 + threadIdx.x;   // quad index
    const float* src; ushort_t* dst; int lo;
    if (g < 98304)        { src = in_proj_w;  dst = wball;           lo = g; }
    else if (g < 131072)  { src = out_proj_w; dst = wball + 393216;  lo = g - 98304; }
    else if (g < 1179648) { src = w1;         dst = wball + 524288;  lo = g - 131072; }
    else                  { src = w2;         dst = wball + 4718592; lo = g - 1179648; }
    float4 v = *(const float4*)(src + (size_t)lo * 4);
    ushort_t o[4] = { bf16r(v.x), bf16r(v.y), bf16r(v.z), bf16r(v.w) };
    *(uint2*)(dst + (size_t)lo * 4) = *(uint2*)o;
}

// ---------------------------------------------------------------------------
// Embedding + positional encoding + pad mask. Writes h (fp32) and hb (bf16).
// ---------------------------------------------------------------------------
__global__ __launch_bounds__(256) void embed_kernel(
    const int* __restrict__ x, const float* __restrict__ emb,
    float* __restrict__ h, ushort_t* __restrict__ hb, int* __restrict__ pad)
{
    __shared__ float wred[4];
    const int n = blockIdx.x;
    const int d = threadIdx.x;
    const int wave = d >> 6;
    const int s = n & (SEQ - 1);
    const int tok = x[n];
    float v = emb[tok * D_MODEL + d] * 16.0f;   // sqrt(256)
    const int j = d >> 1;
    const float c = -9.210340371976184f / 256.0f;
    const float div = expf((float)(2 * j) * c);
    const float ang = (float)s * div;
    v += (d & 1) ? cosf(ang) : sinf(ang);
    h[n * D_MODEL + d] = v;
    hb[n * D_MODEL + d] = bf16r(v);
    float sm = v;
    for (int o = 1; o < 64; o <<= 1) sm += __shfl_xor(sm, o);
    if ((d & 63) == 0) wred[wave] = sm;
    __syncthreads();
    if (d == 0) pad[n] = ((wred[0] + wred[1] + wred[2] + wred[3]) == 0.0f) ? 1 : 0;
}

// ---------------------------------------------------------------------------
// m97-style 128x128 bf16 MFMA GEMM: C[M,N] = A[M,K] @ B[N,K]^T + bias[N]
// BK=64, 256 threads = 4 waves (2x2), wave tile 64x64 (4x4 16x16x32 frags).
// Staging via global_load_lds width=16: zero staging VGPRs, no
// live-across-barrier values (round-5/7 spill root cause eliminated).
// LDS rows UNPADDED (global_load_lds lane-contiguity requirement).
// Requires N % 128 == 0 (true for all call sites: 768/256/1024/256).
// Segmented (MoE) mode when counts != nullptr (padded stride CSTRIDE).
// ---------------------------------------------------------------------------
#define GF_RELU    1
#define GF_OUTBF16 2
#define GF_GATHER  4
#define GF_SCATTER 8

__global__ __launch_bounds__(256, 1) void gemm_gl(
    const ushort_t* __restrict__ A, const ushort_t* __restrict__ Bw,
    const float* __restrict__ bias, void* __restrict__ Cout,
    int M, int N, int K,
    const int* __restrict__ counts,
    const int* __restrict__ perm, const float* __restrict__ topw,
    int flags)
{
    __shared__ ushort_t As[128 * 64];   // 16 KB, unpadded 128 B rows
    __shared__ ushort_t Bs[128 * 64];   // 16 KB
    const int e = blockIdx.z;
    int cnt, off = 0;
    if (counts) {
        cnt = counts[e * CSTRIDE];
        if ((int)blockIdx.y * 128 >= cnt) return;
        for (int i = 0; i < e; i++) off += counts[i * CSTRIDE];
    } else { cnt = M; }
    const ushort_t* Bp = Bw + (size_t)e * N * K;
    const float* bp = bias + (size_t)e * N;
    const int m0 = blockIdx.y * 128, n0 = blockIdx.x * 128;
    const int tid = threadIdx.x;
    const int lane = tid & 63, wave = tid >> 6;
    const int r8 = lane >> 3;           // 0..7  (row within 8-row DMA chunk)
    const int kc = (lane & 7) * 8;      // 0..56 (k element offset)
    // Per-lane A source row index for each of the wave's 4 DMA chunks.
    size_t asrc[4];
#pragma unroll
    for (int c = 0; c < 4; c++) {
        const int gr = m0 + wave * 32 + c * 8 + r8;
        const bool v = gr < cnt;
        if (flags & GF_GATHER) asrc[c] = (size_t)perm[off + (v ? gr : m0)];
        else                   asrc[c] = (size_t)(off + (v ? gr : m0));
    }
    const int wm = (wave & 1) * 64, wn = (wave >> 1) * 64;
    const int fr = lane & 15, fk = (lane >> 4) * 8;
    floatx4 acc[4][4];
#pragma unroll
    for (int i = 0; i < 4; i++)
#pragma unroll
        for (int jj = 0; jj < 4; jj++) acc[i][jj] = (floatx4){0.f, 0.f, 0.f, 0.f};

    for (int k0 = 0; k0 < K; k0 += 64) {
        __syncthreads();   // previous iteration's readers done
#pragma unroll
        for (int c = 0; c < 4; c++) {
            const int rowb = wave * 32 + c * 8;   // wave-uniform LDS base row
            GLD16(A + asrc[c] * K + k0 + kc, &As[rowb * 64]);
            GLD16(Bp + (size_t)(n0 + rowb + r8) * K + k0 + kc, &Bs[rowb * 64]);
        }
        __syncthreads();   // DMA drained (compiler emits vmcnt(0) before barrier)
#pragma unroll
        for (int ks = 0; ks < 2; ks++) {
            const int ko = ks * 32 + fk;
            short8 fa[4], fb[4];
#pragma unroll
            for (int m = 0; m < 4; m++)
                fa[m] = *(const short8*)&As[(wm + m * 16 + fr) * 64 + ko];
#pragma unroll
            for (int n = 0; n < 4; n++)
                fb[n] = *(const short8*)&Bs[(wn + n * 16 + fr) * 64 + ko];
#pragma unroll
            for (int m = 0; m < 4; m++)
#pragma unroll
                for (int n = 0; n < 4; n++)
                    acc[m][n] = __builtin_amdgcn_mfma_f32_16x16x32_bf16(fa[m], fb[n], acc[m][n], 0, 0, 0);
        }
    }
    const int crow0 = (lane >> 4) * 4;
    const int ccol = lane & 15;
#pragma unroll
    for (int m = 0; m < 4; m++) {
#pragma unroll
        for (int n = 0; n < 4; n++) {
            const int gcol = n0 + wn + n * 16 + ccol;
            const float bsv = bp[gcol];
#pragma unroll
            for (int r = 0; r < 4; r++) {
                const int grow = m0 + wm + m * 16 + crow0 + r;
                if (grow >= cnt) continue;
                float v = acc[m][n][r] + bsv;
                if (flags & GF_RELU) v = fmaxf(v, 0.f);
                if (flags & GF_SCATTER) {
                    const int tok = perm[off + grow];
                    ((float*)Cout)[(size_t)tok * N + gcol] = v * topw[tok];
                } else if (flags & GF_OUTBF16) {
                    ((ushort_t*)Cout)[(size_t)(off + grow) * N + gcol] = bf16r(v);
                } else {
                    ((float*)Cout)[(size_t)(off + grow) * N + gcol] = v;
                }
            }
        }
    }
}

// ---------------------------------------------------------------------------
// MFMA flash-style attention (verified round 3).
// ---------------------------------------------------------------------------
__global__ __launch_bounds__(256) void attn_kernel(
    const ushort_t* __restrict__ qkvb, const int* __restrict__ pad,
    ushort_t* __restrict__ ctxb)
{
    __shared__ ushort_t Kt[64 * 40];
    __shared__ ushort_t Vt[32 * 72];
    __shared__ ushort_t Ps[64 * 72];
    __shared__ float padf[512];
    const int tid = threadIdx.x;
    const int lane = tid & 63;
    const int wave = tid >> 6;
    const int quad = lane >> 4;
    const int l16  = lane & 15;
    const int bid = blockIdx.x;
    const int qt = bid & 7;
    const int hh = (bid >> 3) & 7;
    const int b = bid >> 6;
    const int q0 = wave * 16;

    padf[tid]       = (float)pad[b * SEQ + tid];
    padf[tid + 256] = (float)pad[b * SEQ + 256 + tid];

    short8 qfrag = *(const short8*)(qkvb +
        (size_t)(b * SEQ + qt * 64 + q0 + l16) * 768 + hh * 32 + quad * 8);

    const int skey = tid >> 2;
    const int schunk = (tid & 3) * 8;

    floatx4 o0 = {0.f,0.f,0.f,0.f}, o1 = {0.f,0.f,0.f,0.f};
    float lsum[4] = {0.f, 0.f, 0.f, 0.f};
    const float scale = 0.17677669529663687f;

    for (int t = 0; t < 8; t++) {
        const int kbase = b * SEQ + t * 64;
        __syncthreads();
        uint4 kv = *(const uint4*)(qkvb + (size_t)(kbase + skey) * 768 + 256 + hh * 32 + schunk);
        *(uint4*)&Kt[skey * 40 + schunk] = kv;
        uint4 vv = *(const uint4*)(qkvb + (size_t)(kbase + skey) * 768 + 512 + hh * 32 + schunk);
        ushort_t vs[8]; *(uint4*)vs = vv;
#pragma unroll
        for (int j = 0; j < 8; j++) {
            const int d = schunk + j;
            Vt[d * 72 + (skey ^ ((d >> 3) << 3))] = vs[j];
        }
        __syncthreads();
        floatx4 sfr[4];
#pragma unroll
        for (int fn = 0; fn < 4; fn++) {
            short8 kf = *(const short8*)&Kt[(fn * 16 + l16) * 40 + quad * 8];
            sfr[fn] = __builtin_amdgcn_mfma_f32_16x16x32_bf16(
                qfrag, kf, (floatx4){0.f,0.f,0.f,0.f}, 0, 0, 0);
        }
#pragma unroll
        for (int fn = 0; fn < 4; fn++) {
            const int keyl = fn * 16 + l16;
            const float pv = padf[t * 64 + keyl];
#pragma unroll
            for (int r = 0; r < 4; r++) {
                float p = (pv != 0.f) ? 0.f : __expf(sfr[fn][r] * scale);
                ushort_t pb = bf16r(p);
                lsum[r] += bf2f(pb);
                Ps[(q0 + quad * 4 + r) * 72 + keyl] = pb;
            }
        }
#pragma unroll
        for (int kc = 0; kc < 2; kc++) {
            short8 pf = *(const short8*)&Ps[(q0 + l16) * 72 + kc * 32 + quad * 8];
            {
                const int d = l16;
                short8 vf = *(const short8*)&Vt[d * 72 + ((kc * 32 + quad * 8) ^ ((d >> 3) << 3))];
                o0 = __builtin_amdgcn_mfma_f32_16x16x32_bf16(pf, vf, o0, 0, 0, 0);
            }
            {
                const int d = 16 + l16;
                short8 vf = *(const short8*)&Vt[d * 72 + ((kc * 32 + quad * 8) ^ ((d >> 3) << 3))];
                o1 = __builtin_amdgcn_mfma_f32_16x16x32_bf16(pf, vf, o1, 0, 0, 0);
            }
        }
    }
#pragma unroll
    for (int r = 0; r < 4; r++) {
        float v = lsum[r];
        v += __shfl_xor(v, 1); v += __shfl_xor(v, 2);
        v += __shfl_xor(v, 4); v += __shfl_xor(v, 8);
        lsum[r] = 1.f / v;
    }
    const int nq = b * SEQ + qt * 64 + q0 + quad * 4;
#pragma unroll
    for (int r = 0; r < 4; r++) {
        ushort_t* outp = ctxb + (size_t)(nq + r) * 256 + hh * 32;
        outp[l16]      = bf16r(o0[r] * lsum[r]);
        outp[16 + l16] = bf16r(o1[r] * lsum[r]);
    }
}

// ---------------------------------------------------------------------------
// Residual add + LayerNorm (in place into h, plus bf16 copy hb).
// ---------------------------------------------------------------------------
__global__ __launch_bounds__(256) void add_ln(
    float* __restrict__ h, const float* __restrict__ add,
    const float* __restrict__ g, const float* __restrict__ b,
    ushort_t* __restrict__ hb)
{
    __shared__ float wred[8];
    const int n = blockIdx.x;
    const int d = threadIdx.x;
    const int wave = d >> 6;
    const float v = h[n * D_MODEL + d] + add[n * D_MODEL + d];
    float s = v;
    for (int o = 1; o < 64; o <<= 1) s += __shfl_xor(s, o);
    if ((d & 63) == 0) wred[wave] = s;
    __syncthreads();
    const float mu = (wred[0] + wred[1] + wred[2] + wred[3]) * (1.0f / 256.0f);
    const float c = v - mu;
    float cs = c * c;
    for (int o = 1; o < 64; o <<= 1) cs += __shfl_xor(cs, o);
    if ((d & 63) == 0) wred[4 + wave] = cs;
    __syncthreads();
    const float var = (wred[4] + wred[5] + wred[6] + wred[7]) * (1.0f / 256.0f);
    const float o = c * rsqrtf(var + 1e-5f) * g[d] + b[d];
    h[n * D_MODEL + d] = o;
    hb[n * D_MODEL + d] = bf16r(o);
}

// ---------------------------------------------------------------------------
// Gate v2 (verified round 4): 128 tokens/block, LDS histogram, 8 padded
// global atomics per block.
// ---------------------------------------------------------------------------
__global__ __launch_bounds__(256) void gate_kernel(
    const float* __restrict__ h, const float* __restrict__ gw,
    const float* __restrict__ gb, int* __restrict__ top_idx,
    float* __restrict__ top_w, int* __restrict__ pos, int* __restrict__ counts)
{
    __shared__ int lidx[128];
    __shared__ int lpos[128];
    __shared__ int hist[NE];
    __shared__ int base[NE];
    const int wave = threadIdx.x >> 6;
    const int lane = threadIdx.x & 63;
    const int t0 = blockIdx.x * 128 + wave * 32;
    float4 gwr[NE];
#pragma unroll
    for (int e = 0; e < NE; e++)
        gwr[e] = *(const float4*)&gw[e * D_MODEL + lane * 4];
    float gbr[NE];
#pragma unroll
    for (int e = 0; e < NE; e++) gbr[e] = gb[e];

    for (int i = 0; i < 32; i++) {
        const int n = t0 + i;
        float4 hv = *(const float4*)&h[(size_t)n * D_MODEL + lane * 4];
        float lg[NE];
#pragma unroll
        for (int e = 0; e < NE; e++)
            lg[e] = hv.x * gwr[e].x + hv.y * gwr[e].y + hv.z * gwr[e].z + hv.w * gwr[e].w;
#pragma unroll
        for (int e = 0; e < NE; e++) {
            float v = lg[e];
            for (int o = 1; o < 64; o <<= 1) v += __shfl_xor(v, o);
            lg[e] = v;
        }
        if (lane == 0) {
            float best = -1e30f; int bi = 0;
#pragma unroll
            for (int e = 0; e < NE; e++) {
                lg[e] += gbr[e];
                if (lg[e] > best) { best = lg[e]; bi = e; }
            }
            float ssum = 0.0f;
#pragma unroll
            for (int e = 0; e < NE; e++) ssum += __expf(lg[e] - best);
            top_idx[n] = bi;
            top_w[n] = 1.0f / ssum;
            lidx[wave * 32 + i] = bi;
        }
    }
    __syncthreads();
    if (threadIdx.x < NE) hist[threadIdx.x] = 0;
    __syncthreads();
    if (threadIdx.x < 128)
        lpos[threadIdx.x] = atomicAdd(&hist[lidx[threadIdx.x]], 1);
    __syncthreads();
    if (threadIdx.x < NE)
        base[threadIdx.x] = atomicAdd(&counts[threadIdx.x * CSTRIDE], hist[threadIdx.x]);
    __syncthreads();
    if (threadIdx.x < 128)
        pos[blockIdx.x * 128 + threadIdx.x] = base[lidx[threadIdx.x]] + lpos[threadIdx.x];
}

__global__ __launch_bounds__(256) void scatter_perm(
    const int* __restrict__ top_idx, const int* __restrict__ pos,
    const int* __restrict__ counts, int* __restrict__ perm)
{
    __shared__ int offs_s[NE];
    if (threadIdx.x < NE) {
        int a = 0;
        for (int i = 0; i < (int)threadIdx.x; i++) a += counts[i * CSTRIDE];
        offs_s[threadIdx.x] = a;
    }
    __syncthreads();
    const int n = blockIdx.x * 256 + threadIdx.x;
    if (n < NTOK) perm[offs_s[top_idx[n]] + pos[n]] = n;
}

// ---------------------------------------------------------------------------
// Masked mean pool, stage 1: 16x16 blocks, partial sums via atomics.
// ---------------------------------------------------------------------------
__global__ __launch_bounds__(256) void pool1(
    const float* __restrict__ h, const int* __restrict__ pad,
    float* __restrict__ pooled, float* __restrict__ cntb)
{
    const int b = blockIdx.x, c = blockIdx.y, d = threadIdx.x;
    float s = 0.0f; int cnt = 0;
    for (int i = 0; i < 32; i++) {
        const int idx = b * SEQ + c * 32 + i;
        if (!pad[idx]) { s += h[(size_t)idx * D_MODEL + d]; cnt++; }
    }
    atomicAdd(&pooled[b * D_MODEL + d], s);
    if (d == 0) atomicAdd(&cntb[b], (float)cnt);
}

__global__ __launch_bounds__(128) void cls_kernel(
    const float* __restrict__ pooled, const float* __restrict__ cntb,
    const float* __restrict__ fc1w, const float* __restrict__ fc1b,
    const float* __restrict__ fc2w, const float* __restrict__ fc2b,
    float* __restrict__ out)
{
    __shared__ float zs[128];
    const int b = blockIdx.x;
    const int j = threadIdx.x;
    const float invc = 1.0f / fmaxf(cntb[b], 1.0f);
    float s = 0.0f;
    for (int d = 0; d < D_MODEL; d++) s += pooled[b * D_MODEL + d] * fc1w[j * D_MODEL + d];
    zs[j] = fmaxf(s * invc + fc1b[j], 0.0f);
    __syncthreads();
    if (j < 2) {
        float o = fc2b[j];
        for (int i = 0; i < 128; i++) o += zs[i] * fc2w[j * 128 + i];
        out[b * 2 + j] = o;
    }
}

// ---------------------------------------------------------------------------
extern "C" void kernel_launch(void* const* d_in, const int* in_sizes, int n_in,
                              void* d_out, int out_size, void* d_ws, size_t ws_size,
                              hipStream_t stream)
{
    const int*   x          = (const int*)d_in[0];
    const float* emb        = (const float*)d_in[1];
    const float* in_proj_w  = (const float*)d_in[2];
    const float* in_proj_b  = (const float*)d_in[3];
    const float* out_proj_w = (const float*)d_in[4];
    const float* out_proj_b = (const float*)d_in[5];
    const float* ln1_g      = (const float*)d_in[6];
    const float* ln1_b      = (const float*)d_in[7];
    const float* ln2_g      = (const float*)d_in[8];
    const float* ln2_b      = (const float*)d_in[9];
    const float* gate_w     = (const float*)d_in[10];
    const float* gate_b     = (const float*)d_in[11];
    const float* w1         = (const float*)d_in[12];
    const float* b1         = (const float*)d_in[13];
    const float* w2         = (const float*)d_in[14];
    const float* b2         = (const float*)d_in[15];
    const float* fc1_w      = (const float*)d_in[16];
    const float* fc1_b      = (const float*)d_in[17];
    const float* fc2_w      = (const float*)d_in[18];
    const float* fc2_b      = (const float*)d_in[19];
    float* out = (float*)d_out;

    // workspace layout (float slots)
    float* ws = (float*)d_ws;
    float*    h      = ws;                          // 2,097,152 f
    float*    tmp    = ws + 2097152;                // 2,097,152 f
    ushort_t* qkvb   = (ushort_t*)(ws + 4194304);   // 8192*768 bf16
    ushort_t* ctxb   = (ushort_t*)(ws + 7340032);   // 8192*256 bf16
    ushort_t* ehb    = (ushort_t*)(ws + 4194304);   // 8192*1024 bf16 aliases qkvb+ctxb
    ushort_t* hb     = (ushort_t*)(ws + 8388608);   // 8192*256 bf16
    float*    top_w  = ws + 10485760;               // 8192
    float*    pooled = ws + 10493952;               // 4096
    float*    cntb   = ws + 10498048;               // 16
    int* ipart   = (int*)(ws + 10498064);
    int* pad     = ipart;              // 8192
    int* top_idx = ipart + 8192;
    int* pos     = ipart + 16384;
    int* perm    = ipart + 24576;
    int* counts  = ipart + 32768;      // NE*CSTRIDE
    ushort_t* wball = (ushort_t*)(ws + 10531088);   // 8,912,896 bf16 (17.8 MB)

    // all-weight bf16 conversion, one launch
    wconv_all<<<8704, 256, 0, stream>>>(in_proj_w, out_proj_w, w1, w2, wball);
    embed_kernel<<<NTOK, 256, 0, stream>>>(x, emb, h, hb, pad);
    hipMemsetAsync(pooled, 0, (NB * D_MODEL + NB) * sizeof(float), stream);

    for (int l = 0; l < 2; l++) {
        const ushort_t* inb_l  = wball + (size_t)l * 196608;
        const ushort_t* outb_l = wball + 393216 + (size_t)l * 65536;
        const ushort_t* w1b_l  = wball + 524288 + (size_t)l * 2097152;
        const ushort_t* w2b_l  = wball + 4718592 + (size_t)l * 2097152;

        // --- qkv projection: [8192,256] x [768,256]^T -> qkvb (bf16) ---
        gemm_gl<<<dim3(768 / 128, NTOK / 128, 1), 256, 0, stream>>>(
            hb, inb_l, in_proj_b + l * 768, qkvb, NTOK, 768, 256,
            nullptr, nullptr, nullptr, GF_OUTBF16);
        // --- attention (MFMA flash) -> ctxb ---
        attn_kernel<<<NB * NH * (SEQ / 64), 256, 0, stream>>>(qkvb, pad, ctxb);
        // --- output projection -> tmp (fp32) ---
        gemm_gl<<<dim3(256 / 128, NTOK / 128, 1), 256, 0, stream>>>(
            ctxb, outb_l, out_proj_b + l * 256, tmp, NTOK, 256, 256,
            nullptr, nullptr, nullptr, 0);
        add_ln<<<NTOK, 256, 0, stream>>>(h, tmp, ln1_g + l * 256, ln1_b + l * 256, hb);
        // --- MoE routing ---
        hipMemsetAsync(counts, 0, NE * CSTRIDE * sizeof(int), stream);
        gate_kernel<<<NTOK / 128, 256, 0, stream>>>(
            h, gate_w + l * NE * 256, gate_b + l * NE, top_idx, top_w, pos, counts);
        scatter_perm<<<NTOK / 256, 256, 0, stream>>>(top_idx, pos, counts, perm);
        // --- MoE expert GEMMs (routed expert only) ---
        gemm_gl<<<dim3(EHID / 128, NTOK / 128, NE), 256, 0, stream>>>(
            hb, w1b_l, b1 + l * NE * EHID, ehb, 0, EHID, 256,
            counts, perm, nullptr, GF_GATHER | GF_RELU | GF_OUTBF16);
        gemm_gl<<<dim3(D_MODEL / 128, NTOK / 128, NE), 256, 0, stream>>>(
            ehb, w2b_l, b2 + l * NE * 256, tmp, 0, D_MODEL, 1024,
            counts, perm, top_w, GF_SCATTER);
        add_ln<<<NTOK, 256, 0, stream>>>(h, tmp, ln2_g + l * 256, ln2_b + l * 256, hb);
    }

    pool1<<<dim3(NB, 16), 256, 0, stream>>>(h, pad, pooled, cntb);
    cls_kernel<<<NB, 128, 0, stream>>>(pooled, cntb, fc1_w, fc1_b, fc2_w, fc2_b, out);
}

// Round 9
// 443.082 us; speedup vs baseline: 1.9943x; 1.2476x over previous
//
#include <hip/hip_runtime.h>
#include <math.h>

#define D_MODEL 256
#define NTOK    8192
#define SEQ     512
#define NB      16
#define NH      8
#define DHEAD   32
#define NE      8
#define EHID    1024
#define CSTRIDE 32

typedef __attribute__((ext_vector_type(8))) short short8;
typedef __attribute__((ext_vector_type(4))) float floatx4;
typedef unsigned short ushort_t;

__device__ __forceinline__ ushort_t bf16r(float f) {
    unsigned int u = __float_as_uint(f);
    u += 0x7fffu + ((u >> 16) & 1u);
    return (ushort_t)(u >> 16);
}
__device__ __forceinline__ float bf2f(ushort_t b) {
    return __uint_as_float(((unsigned)b) << 16);
}

#define GLD16(gsrc, ldst) \
    __builtin_amdgcn_global_load_lds( \
        (const __attribute__((address_space(1))) void*)(gsrc), \
        (__attribute__((address_space(3))) void*)(ldst), 16, 0, 0)

// ---------------------------------------------------------------------------
__global__ __launch_bounds__(256) void wconv_all(
    const float* __restrict__ in_proj_w, const float* __restrict__ out_proj_w,
    const float* __restrict__ w1, const float* __restrict__ w2,
    ushort_t* __restrict__ wball)
{
    const int g = blockIdx.x * 256 + threadIdx.x;
    const float* src; ushort_t* dst; int lo;
    if (g < 98304)        { src = in_proj_w;  dst = wball;           lo = g; }
    else if (g < 131072)  { src = out_proj_w; dst = wball + 393216;  lo = g - 98304; }
    else if (g < 1179648) { src = w1;         dst = wball + 524288;  lo = g - 131072; }
    else                  { src = w2;         dst = wball + 4718592; lo = g - 1179648; }
    float4 v = *(const float4*)(src + (size_t)lo * 4);
    ushort_t o[4] = { bf16r(v.x), bf16r(v.y), bf16r(v.z), bf16r(v.w) };
    *(uint2*)(dst + (size_t)lo * 4) = *(uint2*)o;
}

// ---------------------------------------------------------------------------
__global__ __launch_bounds__(256) void embed_kernel(
    const int* __restrict__ x, const float* __restrict__ emb,
    float* __restrict__ h, ushort_t* __restrict__ hb, int* __restrict__ pad)
{
    __shared__ float wred[4];
    const int n = blockIdx.x;
    const int d = threadIdx.x;
    const int wave = d >> 6;
    const int s = n & (SEQ - 1);
    const int tok = x[n];
    float v = emb[tok * D_MODEL + d] * 16.0f;
    const int j = d >> 1;
    const float c = -9.210340371976184f / 256.0f;
    const float div = expf((float)(2 * j) * c);
    const float ang = (float)s * div;
    v += (d & 1) ? cosf(ang) : sinf(ang);
    h[n * D_MODEL + d] = v;
    hb[n * D_MODEL + d] = bf16r(v);
    float sm = v;
    for (int o = 1; o < 64; o <<= 1) sm += __shfl_xor(sm, o);
    if ((d & 63) == 0) wred[wave] = sm;
    __syncthreads();
    if (d == 0) pad[n] = ((wred[0] + wred[1] + wred[2] + wred[3]) == 0.0f) ? 1 : 0;
}

// ---------------------------------------------------------------------------
// 64x64 bf16 MFMA GEMM with global_load_lds staging + XOR swizzle.
// BK=64, 256 threads (4 waves 2x2, wave tile 32x32, 2x2 frags).
// LDS[row][chunk p] = G[row][chunk p ^ (row&7)]; reader applies same XOR.
// Zero staging VGPRs (no spill), 16 KB LDS (8 blocks/CU), grid parallelism
// identical to the verified round-6 kernel. Requires N,M-tiles %64, K%64.
// ---------------------------------------------------------------------------
#define GF_RELU    1
#define GF_OUTBF16 2
#define GF_GATHER  4
#define GF_SCATTER 8

__global__ __launch_bounds__(256) void gemm_gl64(
    const ushort_t* __restrict__ A, const ushort_t* __restrict__ Bw,
    const float* __restrict__ bias, void* __restrict__ Cout,
    int M, int N, int K,
    const int* __restrict__ counts,
    const int* __restrict__ perm, const float* __restrict__ topw,
    int flags)
{
    __shared__ ushort_t As[64 * 64];   // 8 KB, unpadded (DMA layout)
    __shared__ ushort_t Bs[64 * 64];
    const int e = blockIdx.z;
    int cnt, off = 0;
    if (counts) {
        cnt = counts[e * CSTRIDE];
        if ((int)blockIdx.y * 64 >= cnt) return;
        for (int i = 0; i < e; i++) off += counts[i * CSTRIDE];
    } else { cnt = M; }
    const ushort_t* Bp = Bw + (size_t)e * N * K;
    const float* bp = bias + (size_t)e * N;
    const int m0 = blockIdx.y * 64, n0 = blockIdx.x * 64;
    const int tid = threadIdx.x;
    const int lane = tid & 63, wave = tid >> 6;
    const int r8 = lane >> 3;            // 0..7: row within 8-row DMA chunk
    const int p  = lane & 7;             // 0..7: LDS chunk slot
    const int kswz = ((p ^ r8) << 3);    // swizzled source k-offset (elems)
    const int row0 = wave * 16;          // this wave's 16 staging rows
    size_t asrc[2], bsrc[2];
#pragma unroll
    for (int c = 0; c < 2; c++) {
        const int gr = m0 + row0 + c * 8 + r8;
        const int grc = (gr < cnt) ? gr : m0;
        asrc[c] = (flags & GF_GATHER) ? (size_t)perm[off + grc] : (size_t)(off + grc);
        bsrc[c] = (size_t)(n0 + row0 + c * 8 + r8);
    }
    const int quad = lane >> 4, fr = lane & 15;
    const int wm = (wave & 1) * 32, wn = (wave >> 1) * 32;
    floatx4 acc[2][2];
#pragma unroll
    for (int i = 0; i < 2; i++)
#pragma unroll
        for (int jj = 0; jj < 2; jj++) acc[i][jj] = (floatx4){0.f, 0.f, 0.f, 0.f};

    for (int k0 = 0; k0 < K; k0 += 64) {
        __syncthreads();
#pragma unroll
        for (int c = 0; c < 2; c++) {
            GLD16(A + asrc[c] * K + k0 + kswz, &As[(row0 + c * 8) * 64]);
            GLD16(Bp + bsrc[c] * K + k0 + kswz, &Bs[(row0 + c * 8) * 64]);
        }
        __syncthreads();
#pragma unroll
        for (int ks = 0; ks < 2; ks++) {
            const int sw = (((ks * 4 + quad) ^ (fr & 7)) << 3);
            short8 fa0 = *(const short8*)&As[(wm + fr) * 64 + sw];
            short8 fa1 = *(const short8*)&As[(wm + 16 + fr) * 64 + sw];
            short8 fb0 = *(const short8*)&Bs[(wn + fr) * 64 + sw];
            short8 fb1 = *(const short8*)&Bs[(wn + 16 + fr) * 64 + sw];
            acc[0][0] = __builtin_amdgcn_mfma_f32_16x16x32_bf16(fa0, fb0, acc[0][0], 0, 0, 0);
            acc[0][1] = __builtin_amdgcn_mfma_f32_16x16x32_bf16(fa0, fb1, acc[0][1], 0, 0, 0);
            acc[1][0] = __builtin_amdgcn_mfma_f32_16x16x32_bf16(fa1, fb0, acc[1][0], 0, 0, 0);
            acc[1][1] = __builtin_amdgcn_mfma_f32_16x16x32_bf16(fa1, fb1, acc[1][1], 0, 0, 0);
        }
    }
    const int crow0 = quad * 4;
    const int ccol = fr;
#pragma unroll
    for (int m = 0; m < 2; m++) {
#pragma unroll
        for (int n = 0; n < 2; n++) {
            const int gcol = n0 + wn + n * 16 + ccol;
            const float bsv = bp[gcol];
#pragma unroll
            for (int r = 0; r < 4; r++) {
                const int grow = m0 + wm + m * 16 + crow0 + r;
                if (grow >= cnt) continue;
                float v = acc[m][n][r] + bsv;
                if (flags & GF_RELU) v = fmaxf(v, 0.f);
                if (flags & GF_SCATTER) {
                    const int tok = perm[off + grow];
                    ((float*)Cout)[(size_t)tok * N + gcol] = v * topw[tok];
                } else if (flags & GF_OUTBF16) {
                    ((ushort_t*)Cout)[(size_t)(off + grow) * N + gcol] = bf16r(v);
                } else {
                    ((float*)Cout)[(size_t)(off + grow) * N + gcol] = v;
                }
            }
        }
    }
}

// ---------------------------------------------------------------------------
// MFMA flash-style attention (verified round 3).
// ---------------------------------------------------------------------------
__global__ __launch_bounds__(256) void attn_kernel(
    const ushort_t* __restrict__ qkvb, const int* __restrict__ pad,
    ushort_t* __restrict__ ctxb)
{
    __shared__ ushort_t Kt[64 * 40];
    __shared__ ushort_t Vt[32 * 72];
    __shared__ ushort_t Ps[64 * 72];
    __shared__ float padf[512];
    const int tid = threadIdx.x;
    const int lane = tid & 63;
    const int wave = tid >> 6;
    const int quad = lane >> 4;
    const int l16  = lane & 15;
    const int bid = blockIdx.x;
    const int qt = bid & 7;
    const int hh = (bid >> 3) & 7;
    const int b = bid >> 6;
    const int q0 = wave * 16;

    padf[tid]       = (float)pad[b * SEQ + tid];
    padf[tid + 256] = (float)pad[b * SEQ + 256 + tid];

    short8 qfrag = *(const short8*)(qkvb +
        (size_t)(b * SEQ + qt * 64 + q0 + l16) * 768 + hh * 32 + quad * 8);

    const int skey = tid >> 2;
    const int schunk = (tid & 3) * 8;

    floatx4 o0 = {0.f,0.f,0.f,0.f}, o1 = {0.f,0.f,0.f,0.f};
    float lsum[4] = {0.f, 0.f, 0.f, 0.f};
    const float scale = 0.17677669529663687f;

    for (int t = 0; t < 8; t++) {
        const int kbase = b * SEQ + t * 64;
        __syncthreads();
        uint4 kv = *(const uint4*)(qkvb + (size_t)(kbase + skey) * 768 + 256 + hh * 32 + schunk);
        *(uint4*)&Kt[skey * 40 + schunk] = kv;
        uint4 vv = *(const uint4*)(qkvb + (size_t)(kbase + skey) * 768 + 512 + hh * 32 + schunk);
        ushort_t vs[8]; *(uint4*)vs = vv;
#pragma unroll
        for (int j = 0; j < 8; j++) {
            const int d = schunk + j;
            Vt[d * 72 + (skey ^ ((d >> 3) << 3))] = vs[j];
        }
        __syncthreads();
        floatx4 sfr[4];
#pragma unroll
        for (int fn = 0; fn < 4; fn++) {
            short8 kf = *(const short8*)&Kt[(fn * 16 + l16) * 40 + quad * 8];
            sfr[fn] = __builtin_amdgcn_mfma_f32_16x16x32_bf16(
                qfrag, kf, (floatx4){0.f,0.f,0.f,0.f}, 0, 0, 0);
        }
#pragma unroll
        for (int fn = 0; fn < 4; fn++) {
            const int keyl = fn * 16 + l16;
            const float pv = padf[t * 64 + keyl];
#pragma unroll
            for (int r = 0; r < 4; r++) {
                float p = (pv != 0.f) ? 0.f : __expf(sfr[fn][r] * scale);
                ushort_t pb = bf16r(p);
                lsum[r] += bf2f(pb);
                Ps[(q0 + quad * 4 + r) * 72 + keyl] = pb;
            }
        }
#pragma unroll
        for (int kc = 0; kc < 2; kc++) {
            short8 pf = *(const short8*)&Ps[(q0 + l16) * 72 + kc * 32 + quad * 8];
            {
                const int d = l16;
                short8 vf = *(const short8*)&Vt[d * 72 + ((kc * 32 + quad * 8) ^ ((d >> 3) << 3))];
                o0 = __builtin_amdgcn_mfma_f32_16x16x32_bf16(pf, vf, o0, 0, 0, 0);
            }
            {
                const int d = 16 + l16;
                short8 vf = *(const short8*)&Vt[d * 72 + ((kc * 32 + quad * 8) ^ ((d >> 3) << 3))];
                o1 = __builtin_amdgcn_mfma_f32_16x16x32_bf16(pf, vf, o1, 0, 0, 0);
            }
        }
    }
#pragma unroll
    for (int r = 0; r < 4; r++) {
        float v = lsum[r];
        v += __shfl_xor(v, 1); v += __shfl_xor(v, 2);
        v += __shfl_xor(v, 4); v += __shfl_xor(v, 8);
        lsum[r] = 1.f / v;
    }
    const int nq = b * SEQ + qt * 64 + q0 + quad * 4;
#pragma unroll
    for (int r = 0; r < 4; r++) {
        ushort_t* outp = ctxb + (size_t)(nq + r) * 256 + hh * 32;
        outp[l16]      = bf16r(o0[r] * lsum[r]);
        outp[16 + l16] = bf16r(o1[r] * lsum[r]);
    }
}

// ---------------------------------------------------------------------------
// Residual add + LayerNorm; optional fused gate logits+argmax (block = token,
// which holds the full 256-dim row, so the gate dot-products are 8 block
// reductions — no serial token loop, no extra h read from HBM).
// ---------------------------------------------------------------------------
template<bool GATE>
__global__ __launch_bounds__(256) void add_ln_t(
    float* __restrict__ h, const float* __restrict__ add,
    const float* __restrict__ g, const float* __restrict__ b,
    ushort_t* __restrict__ hb,
    const float* __restrict__ gw, const float* __restrict__ gb,
    int* __restrict__ top_idx, float* __restrict__ top_w)
{
    __shared__ float wred[8];
    __shared__ float ered[NE][4];
    const int n = blockIdx.x;
    const int d = threadIdx.x;
    const int wave = d >> 6;
    const float v = h[n * D_MODEL + d] + add[n * D_MODEL + d];
    float s = v;
    for (int o = 1; o < 64; o <<= 1) s += __shfl_xor(s, o);
    if ((d & 63) == 0) wred[wave] = s;
    __syncthreads();
    const float mu = (wred[0] + wred[1] + wred[2] + wred[3]) * (1.0f / 256.0f);
    const float c = v - mu;
    float cs = c * c;
    for (int o = 1; o < 64; o <<= 1) cs += __shfl_xor(cs, o);
    if ((d & 63) == 0) wred[4 + wave] = cs;
    __syncthreads();
    const float var = (wred[4] + wred[5] + wred[6] + wred[7]) * (1.0f / 256.0f);
    const float o = c * rsqrtf(var + 1e-5f) * g[d] + b[d];
    h[n * D_MODEL + d] = o;
    hb[n * D_MODEL + d] = bf16r(o);
    if (GATE) {
#pragma unroll
        for (int e = 0; e < NE; e++) {
            float pe = o * gw[e * D_MODEL + d];
            for (int of = 1; of < 64; of <<= 1) pe += __shfl_xor(pe, of);
            if ((d & 63) == 0) ered[e][wave] = pe;
        }
        __syncthreads();
        if (d == 0) {
            float best = -1e30f; int bi = 0;
            float lg[NE];
#pragma unroll
            for (int e = 0; e < NE; e++) {
                lg[e] = ered[e][0] + ered[e][1] + ered[e][2] + ered[e][3] + gb[e];
                if (lg[e] > best) { best = lg[e]; bi = e; }
            }
            float ssum = 0.0f;
#pragma unroll
            for (int e = 0; e < NE; e++) ssum += __expf(lg[e] - best);
            top_idx[n] = bi;
            top_w[n] = 1.0f / ssum;
        }
    }
}

// ---------------------------------------------------------------------------
// Bucket: per-block LDS histogram of 256 tokens -> 8 padded global atomics.
// ---------------------------------------------------------------------------
__global__ __launch_bounds__(256) void bucket_kernel(
    const int* __restrict__ top_idx, int* __restrict__ pos,
    int* __restrict__ counts)
{
    __shared__ int hist[NE];
    __shared__ int base[NE];
    __shared__ int lpos[256];
    const int n = blockIdx.x * 256 + threadIdx.x;
    if (threadIdx.x < NE) hist[threadIdx.x] = 0;
    __syncthreads();
    const int e = top_idx[n];
    lpos[threadIdx.x] = atomicAdd(&hist[e], 1);
    __syncthreads();
    if (threadIdx.x < NE)
        base[threadIdx.x] = atomicAdd(&counts[threadIdx.x * CSTRIDE], hist[threadIdx.x]);
    __syncthreads();
    pos[n] = base[e] + lpos[threadIdx.x];
}

__global__ __launch_bounds__(256) void scatter_perm(
    const int* __restrict__ top_idx, const int* __restrict__ pos,
    const int* __restrict__ counts, int* __restrict__ perm)
{
    __shared__ int offs_s[NE];
    if (threadIdx.x < NE) {
        int a = 0;
        for (int i = 0; i < (int)threadIdx.x; i++) a += counts[i * CSTRIDE];
        offs_s[threadIdx.x] = a;
    }
    __syncthreads();
    const int n = blockIdx.x * 256 + threadIdx.x;
    if (n < NTOK) perm[offs_s[top_idx[n]] + pos[n]] = n;
}

// ---------------------------------------------------------------------------
__global__ __launch_bounds__(256) void pool1(
    const float* __restrict__ h, const int* __restrict__ pad,
    float* __restrict__ pooled, float* __restrict__ cntb)
{
    const int b = blockIdx.x, c = blockIdx.y, d = threadIdx.x;
    float s = 0.0f; int cnt = 0;
    for (int i = 0; i < 32; i++) {
        const int idx = b * SEQ + c * 32 + i;
        if (!pad[idx]) { s += h[(size_t)idx * D_MODEL + d]; cnt++; }
    }
    atomicAdd(&pooled[b * D_MODEL + d], s);
    if (d == 0) atomicAdd(&cntb[b], (float)cnt);
}

__global__ __launch_bounds__(128) void cls_kernel(
    const float* __restrict__ pooled, const float* __restrict__ cntb,
    const float* __restrict__ fc1w, const float* __restrict__ fc1b,
    const float* __restrict__ fc2w, const float* __restrict__ fc2b,
    float* __restrict__ out)
{
    __shared__ float zs[128];
    const int b = blockIdx.x;
    const int j = threadIdx.x;
    const float invc = 1.0f / fmaxf(cntb[b], 1.0f);
    float s = 0.0f;
    for (int d = 0; d < D_MODEL; d++) s += pooled[b * D_MODEL + d] * fc1w[j * D_MODEL + d];
    zs[j] = fmaxf(s * invc + fc1b[j], 0.0f);
    __syncthreads();
    if (j < 2) {
        float o = fc2b[j];
        for (int i = 0; i < 128; i++) o += zs[i] * fc2w[j * 128 + i];
        out[b * 2 + j] = o;
    }
}

// ---------------------------------------------------------------------------
extern "C" void kernel_launch(void* const* d_in, const int* in_sizes, int n_in,
                              void* d_out, int out_size, void* d_ws, size_t ws_size,
                              hipStream_t stream)
{
    const int*   x          = (const int*)d_in[0];
    const float* emb        = (const float*)d_in[1];
    const float* in_proj_w  = (const float*)d_in[2];
    const float* in_proj_b  = (const float*)d_in[3];
    const float* out_proj_w = (const float*)d_in[4];
    const float* out_proj_b = (const float*)d_in[5];
    const float* ln1_g      = (const float*)d_in[6];
    const float* ln1_b      = (const float*)d_in[7];
    const float* ln2_g      = (const float*)d_in[8];
    const float* ln2_b      = (const float*)d_in[9];
    const float* gate_w     = (const float*)d_in[10];
    const float* gate_b     = (const float*)d_in[11];
    const float* w1         = (const float*)d_in[12];
    const float* b1         = (const float*)d_in[13];
    const float* w2         = (const float*)d_in[14];
    const float* b2         = (const float*)d_in[15];
    const float* fc1_w      = (const float*)d_in[16];
    const float* fc1_b      = (const float*)d_in[17];
    const float* fc2_w      = (const float*)d_in[18];
    const float* fc2_b      = (const float*)d_in[19];
    float* out = (float*)d_out;

    // workspace layout (float slots)
    float* ws = (float*)d_ws;
    float*    h      = ws;                          // 2,097,152
    float*    tmp    = ws + 2097152;                // 2,097,152
    ushort_t* qkvb   = (ushort_t*)(ws + 4194304);   // 8192*768 bf16
    ushort_t* ctxb   = (ushort_t*)(ws + 7340032);   // 8192*256 bf16
    ushort_t* ehb    = (ushort_t*)(ws + 4194304);   // aliases qkvb+ctxb
    ushort_t* hb     = (ushort_t*)(ws + 8388608);   // 8192*256 bf16
    float*    top_w  = ws + 9437184;                // 8192
    // zero-region: pooled(4096) + cntb(16) + counts 2 layers (512)
    float*    pooled = ws + 9445376;
    float*    cntb   = ws + 9449472;
    int*      counts = (int*)(ws + 9449488);        // 2 * NE * CSTRIDE
    int* ipart   = (int*)(ws + 9450000);
    int* pad     = ipart;              // 8192
    int* top_idx = ipart + 8192;
    int* pos     = ipart + 16384;
    int* perm    = ipart + 24576;      // 8192, ends 9482768
    ushort_t* wball = (ushort_t*)(ws + 9482768);    // 8,912,896 bf16

    wconv_all<<<8704, 256, 0, stream>>>(in_proj_w, out_proj_w, w1, w2, wball);
    embed_kernel<<<NTOK, 256, 0, stream>>>(x, emb, h, hb, pad);
    hipMemsetAsync(pooled, 0, (4096 + 16 + 2 * NE * CSTRIDE) * sizeof(float), stream);

    for (int l = 0; l < 2; l++) {
        const ushort_t* inb_l  = wball + (size_t)l * 196608;
        const ushort_t* outb_l = wball + 393216 + (size_t)l * 65536;
        const ushort_t* w1b_l  = wball + 524288 + (size_t)l * 2097152;
        const ushort_t* w2b_l  = wball + 4718592 + (size_t)l * 2097152;
        int* counts_l = counts + l * NE * CSTRIDE;

        // --- qkv projection ---
        gemm_gl64<<<dim3(768 / 64, NTOK / 64, 1), 256, 0, stream>>>(
            hb, inb_l, in_proj_b + l * 768, qkvb, NTOK, 768, 256,
            nullptr, nullptr, nullptr, GF_OUTBF16);
        // --- attention ---
        attn_kernel<<<NB * NH * (SEQ / 64), 256, 0, stream>>>(qkvb, pad, ctxb);
        // --- output projection -> tmp (fp32) ---
        gemm_gl64<<<dim3(256 / 64, NTOK / 64, 1), 256, 0, stream>>>(
            ctxb, outb_l, out_proj_b + l * 256, tmp, NTOK, 256, 256,
            nullptr, nullptr, nullptr, 0);
        // --- residual + LN1 + fused gate logits/argmax ---
        add_ln_t<true><<<NTOK, 256, 0, stream>>>(
            h, tmp, ln1_g + l * 256, ln1_b + l * 256, hb,
            gate_w + l * NE * 256, gate_b + l * NE, top_idx, top_w);
        // --- routing buckets + permutation ---
        bucket_kernel<<<NTOK / 256, 256, 0, stream>>>(top_idx, pos, counts_l);
        scatter_perm<<<NTOK / 256, 256, 0, stream>>>(top_idx, pos, counts_l, perm);
        // --- MoE expert GEMMs (routed expert only) ---
        gemm_gl64<<<dim3(EHID / 64, NTOK / 64, NE), 256, 0, stream>>>(
            hb, w1b_l, b1 + l * NE * EHID, ehb, 0, EHID, 256,
            counts_l, perm, nullptr, GF_GATHER | GF_RELU | GF_OUTBF16);
        gemm_gl64<<<dim3(D_MODEL / 64, NTOK / 64, NE), 256, 0, stream>>>(
            ehb, w2b_l, b2 + l * NE * 256, tmp, 0, D_MODEL, 1024,
            counts_l, perm, top_w, GF_SCATTER);
        // --- residual + LN2 ---
        add_ln_t<false><<<NTOK, 256, 0, stream>>>(
            h, tmp, ln2_g + l * 256, ln2_b + l * 256, hb,
            nullptr, nullptr, nullptr, nullptr);
    }

    pool1<<<dim3(NB, 16), 256, 0, stream>>>(h, pad, pooled, cntb);
    cls_kernel<<<NB, 128, 0, stream>>>(pooled, cntb, fc1_w, fc1_b, fc2_w, fc2_b, out);
}

// Round 10
// 397.861 us; speedup vs baseline: 2.2210x; 1.1137x over previous
//
#include <hip/hip_runtime.h>
#include <math.h>

#define D_MODEL 256
#define NTOK    8192
#define SEQ     512
#define NB      16
#define NH      8
#define DHEAD   32
#define NE      8
#define EHID    1024
#define CSTRIDE 32

typedef __attribute__((ext_vector_type(8))) short short8;
typedef __attribute__((ext_vector_type(4))) float floatx4;
typedef unsigned short ushort_t;

__device__ __forceinline__ ushort_t bf16r(float f) {
    unsigned int u = __float_as_uint(f);
    u += 0x7fffu + ((u >> 16) & 1u);
    return (ushort_t)(u >> 16);
}

#define GLD16(gsrc, ldst) \
    __builtin_amdgcn_global_load_lds( \
        (const __attribute__((address_space(1))) void*)(gsrc), \
        (__attribute__((address_space(3))) void*)(ldst), 16, 0, 0)

// ---------------------------------------------------------------------------
__global__ __launch_bounds__(256) void wconv_all(
    const float* __restrict__ in_proj_w, const float* __restrict__ out_proj_w,
    const float* __restrict__ w1, const float* __restrict__ w2,
    ushort_t* __restrict__ wball)
{
    const int g = blockIdx.x * 256 + threadIdx.x;
    const float* src; ushort_t* dst; int lo;
    if (g < 98304)        { src = in_proj_w;  dst = wball;           lo = g; }
    else if (g < 131072)  { src = out_proj_w; dst = wball + 393216;  lo = g - 98304; }
    else if (g < 1179648) { src = w1;         dst = wball + 524288;  lo = g - 131072; }
    else                  { src = w2;         dst = wball + 4718592; lo = g - 1179648; }
    float4 v = *(const float4*)(src + (size_t)lo * 4);
    ushort_t o[4] = { bf16r(v.x), bf16r(v.y), bf16r(v.z), bf16r(v.w) };
    *(uint2*)(dst + (size_t)lo * 4) = *(uint2*)o;
}

// ---------------------------------------------------------------------------
__global__ __launch_bounds__(256) void embed_kernel(
    const int* __restrict__ x, const float* __restrict__ emb,
    float* __restrict__ h, ushort_t* __restrict__ hb, int* __restrict__ pad)
{
    __shared__ float wred[4];
    const int n = blockIdx.x;
    const int d = threadIdx.x;
    const int wave = d >> 6;
    const int s = n & (SEQ - 1);
    const int tok = x[n];
    float v = emb[tok * D_MODEL + d] * 16.0f;
    const int j = d >> 1;
    const float c = -9.210340371976184f / 256.0f;
    const float div = expf((float)(2 * j) * c);
    const float ang = (float)s * div;
    v += (d & 1) ? cosf(ang) : sinf(ang);
    h[n * D_MODEL + d] = v;
    hb[n * D_MODEL + d] = bf16r(v);
    float sm = v;
    for (int o = 1; o < 64; o <<= 1) sm += __shfl_xor(sm, o);
    if ((d & 63) == 0) wred[wave] = sm;
    __syncthreads();
    if (d == 0) pad[n] = ((wred[0] + wred[1] + wred[2] + wred[3]) == 0.0f) ? 1 : 0;
}

// ---------------------------------------------------------------------------
// 64x64 bf16 MFMA GEMM, GLD16 + XOR swizzle (round-9 verified).
// Used for qkv projection and MoE fc1.
// ---------------------------------------------------------------------------
#define GF_RELU    1
#define GF_OUTBF16 2
#define GF_GATHER  4
#define GF_SCATTER 8

__global__ __launch_bounds__(256) void gemm_gl64(
    const ushort_t* __restrict__ A, const ushort_t* __restrict__ Bw,
    const float* __restrict__ bias, void* __restrict__ Cout,
    int M, int N, int K,
    const int* __restrict__ counts,
    const int* __restrict__ perm, const float* __restrict__ topw,
    int flags)
{
    __shared__ ushort_t As[64 * 64];
    __shared__ ushort_t Bs[64 * 64];
    const int e = blockIdx.z;
    int cnt, off = 0;
    if (counts) {
        cnt = counts[e * CSTRIDE];
        if ((int)blockIdx.y * 64 >= cnt) return;
        for (int i = 0; i < e; i++) off += counts[i * CSTRIDE];
    } else { cnt = M; }
    const ushort_t* Bp = Bw + (size_t)e * N * K;
    const float* bp = bias + (size_t)e * N;
    const int m0 = blockIdx.y * 64, n0 = blockIdx.x * 64;
    const int tid = threadIdx.x;
    const int lane = tid & 63, wave = tid >> 6;
    const int r8 = lane >> 3;
    const int p  = lane & 7;
    const int kswz = ((p ^ r8) << 3);
    const int row0 = wave * 16;
    size_t asrc[2], bsrc[2];
#pragma unroll
    for (int c = 0; c < 2; c++) {
        const int gr = m0 + row0 + c * 8 + r8;
        const int grc = (gr < cnt) ? gr : m0;
        asrc[c] = (flags & GF_GATHER) ? (size_t)perm[off + grc] : (size_t)(off + grc);
        bsrc[c] = (size_t)(n0 + row0 + c * 8 + r8);
    }
    const int quad = lane >> 4, fr = lane & 15;
    const int wm = (wave & 1) * 32, wn = (wave >> 1) * 32;
    floatx4 acc[2][2];
#pragma unroll
    for (int i = 0; i < 2; i++)
#pragma unroll
        for (int jj = 0; jj < 2; jj++) acc[i][jj] = (floatx4){0.f, 0.f, 0.f, 0.f};

    for (int k0 = 0; k0 < K; k0 += 64) {
        __syncthreads();
#pragma unroll
        for (int c = 0; c < 2; c++) {
            GLD16(A + asrc[c] * K + k0 + kswz, &As[(row0 + c * 8) * 64]);
            GLD16(Bp + bsrc[c] * K + k0 + kswz, &Bs[(row0 + c * 8) * 64]);
        }
        __syncthreads();
#pragma unroll
        for (int ks = 0; ks < 2; ks++) {
            const int sw = (((ks * 4 + quad) ^ (fr & 7)) << 3);
            short8 fa0 = *(const short8*)&As[(wm + fr) * 64 + sw];
            short8 fa1 = *(const short8*)&As[(wm + 16 + fr) * 64 + sw];
            short8 fb0 = *(const short8*)&Bs[(wn + fr) * 64 + sw];
            short8 fb1 = *(const short8*)&Bs[(wn + 16 + fr) * 64 + sw];
            acc[0][0] = __builtin_amdgcn_mfma_f32_16x16x32_bf16(fa0, fb0, acc[0][0], 0, 0, 0);
            acc[0][1] = __builtin_amdgcn_mfma_f32_16x16x32_bf16(fa0, fb1, acc[0][1], 0, 0, 0);
            acc[1][0] = __builtin_amdgcn_mfma_f32_16x16x32_bf16(fa1, fb0, acc[1][0], 0, 0, 0);
            acc[1][1] = __builtin_amdgcn_mfma_f32_16x16x32_bf16(fa1, fb1, acc[1][1], 0, 0, 0);
        }
    }
    const int crow0 = quad * 4;
    const int ccol = fr;
#pragma unroll
    for (int m = 0; m < 2; m++) {
#pragma unroll
        for (int n = 0; n < 2; n++) {
            const int gcol = n0 + wn + n * 16 + ccol;
            const float bsv = bp[gcol];
#pragma unroll
            for (int r = 0; r < 4; r++) {
                const int grow = m0 + wm + m * 16 + crow0 + r;
                if (grow >= cnt) continue;
                float v = acc[m][n][r] + bsv;
                if (flags & GF_RELU) v = fmaxf(v, 0.f);
                if (flags & GF_SCATTER) {
                    const int tok = perm[off + grow];
                    ((float*)Cout)[(size_t)tok * N + gcol] = v * topw[tok];
                } else if (flags & GF_OUTBF16) {
                    ((ushort_t*)Cout)[(size_t)(off + grow) * N + gcol] = bf16r(v);
                } else {
                    ((float*)Cout)[(size_t)(off + grow) * N + gcol] = v;
                }
            }
        }
    }
}

// ---------------------------------------------------------------------------
// Fused out_proj + residual + LayerNorm1 + gate (logits/argmax/top_w).
// Block = 16 rows x 256 cols (full row -> LN in-block). 4 waves, wave w
// covers cols w*64..w*64+63 (1x4 frags). GLD16+swizzle staging.
// ---------------------------------------------------------------------------
__global__ __launch_bounds__(256) void oproj_ln(
    const ushort_t* __restrict__ Actx, const ushort_t* __restrict__ Wb,
    const float* __restrict__ bias, float* __restrict__ h,
    ushort_t* __restrict__ hb,
    const float* __restrict__ g, const float* __restrict__ b,
    const float* __restrict__ gw, const float* __restrict__ gb,
    int* __restrict__ top_idx, float* __restrict__ top_w)
{
    __shared__ ushort_t As[16 * 64];     // 2 KB
    __shared__ ushort_t Bs[256 * 64];    // 32 KB
    __shared__ float lsum[16][4], lsq[16][4];
    __shared__ float gred[16][NE][4];
    const int m0 = blockIdx.x * 16;
    const int tid = threadIdx.x;
    const int lane = tid & 63, wave = tid >> 6;
    const int r8 = lane >> 3, p = lane & 7;
    const int kswz = ((p ^ r8) << 3);
    const int quad = lane >> 4, fr = lane & 15;
    const int wn = wave * 64;
    floatx4 acc[4];
#pragma unroll
    for (int n = 0; n < 4; n++) acc[n] = (floatx4){0.f, 0.f, 0.f, 0.f};

    for (int k0 = 0; k0 < 256; k0 += 64) {
        __syncthreads();
        if (wave < 2)
            GLD16(Actx + (size_t)(m0 + wave * 8 + r8) * 256 + k0 + kswz,
                  &As[(wave * 8) * 64]);
#pragma unroll
        for (int c = 0; c < 8; c++)
            GLD16(Wb + (size_t)(wn + c * 8 + r8) * 256 + k0 + kswz,
                  &Bs[(wn + c * 8) * 64]);
        __syncthreads();
#pragma unroll
        for (int ks = 0; ks < 2; ks++) {
            const int sw = (((ks * 4 + quad) ^ (fr & 7)) << 3);
            short8 fa = *(const short8*)&As[fr * 64 + sw];
#pragma unroll
            for (int n = 0; n < 4; n++) {
                short8 fb = *(const short8*)&Bs[(wn + n * 16 + fr) * 64 + sw];
                acc[n] = __builtin_amdgcn_mfma_f32_16x16x32_bf16(fa, fb, acc[n], 0, 0, 0);
            }
        }
    }
    // ---- epilogue: bias + residual -> LN -> write -> gate ----
    const int rbase = quad * 4;
    float val[4][4];
#pragma unroll
    for (int n = 0; n < 4; n++) {
        const int col = wn + n * 16 + fr;
        const float bsv = bias[col];
#pragma unroll
        for (int r = 0; r < 4; r++)
            val[r][n] = acc[n][r] + bsv + h[(size_t)(m0 + rbase + r) * 256 + col];
    }
    float s[4], sq[4];
#pragma unroll
    for (int r = 0; r < 4; r++) {
        s[r]  = val[r][0] + val[r][1] + val[r][2] + val[r][3];
        sq[r] = val[r][0] * val[r][0] + val[r][1] * val[r][1]
              + val[r][2] * val[r][2] + val[r][3] * val[r][3];
    }
#pragma unroll
    for (int ox = 1; ox < 16; ox <<= 1)
#pragma unroll
        for (int r = 0; r < 4; r++) {
            s[r] += __shfl_xor(s[r], ox);
            sq[r] += __shfl_xor(sq[r], ox);
        }
    if (fr == 0)
#pragma unroll
        for (int r = 0; r < 4; r++) { lsum[rbase + r][wave] = s[r]; lsq[rbase + r][wave] = sq[r]; }
    __syncthreads();
    float mu[4], rstd[4];
#pragma unroll
    for (int r = 0; r < 4; r++) {
        const int row = rbase + r;
        const float m = (lsum[row][0] + lsum[row][1] + lsum[row][2] + lsum[row][3]) * (1.f / 256.f);
        float v2 = (lsq[row][0] + lsq[row][1] + lsq[row][2] + lsq[row][3]) * (1.f / 256.f) - m * m;
        mu[r] = m;
        rstd[r] = rsqrtf(fmaxf(v2, 0.f) + 1e-5f);
    }
    float o4[4][4];
#pragma unroll
    for (int n = 0; n < 4; n++) {
        const int col = wn + n * 16 + fr;
        const float gc = g[col], bc = b[col];
#pragma unroll
        for (int r = 0; r < 4; r++) {
            const float o = (val[r][n] - mu[r]) * rstd[r] * gc + bc;
            o4[r][n] = o;
            const size_t idx = (size_t)(m0 + rbase + r) * 256 + col;
            h[idx] = o;
            hb[idx] = bf16r(o);
        }
    }
#pragma unroll
    for (int e = 0; e < NE; e++) {
        float ge[4] = {0.f, 0.f, 0.f, 0.f};
#pragma unroll
        for (int n = 0; n < 4; n++) {
            const float gwv = gw[e * 256 + wn + n * 16 + fr];
#pragma unroll
            for (int r = 0; r < 4; r++) ge[r] += o4[r][n] * gwv;
        }
#pragma unroll
        for (int ox = 1; ox < 16; ox <<= 1)
#pragma unroll
            for (int r = 0; r < 4; r++) ge[r] += __shfl_xor(ge[r], ox);
        if (fr == 0)
#pragma unroll
            for (int r = 0; r < 4; r++) gred[rbase + r][e][wave] = ge[r];
    }
    __syncthreads();
    if (tid < 16) {
        const int row = tid;
        float lg[NE];
        float best = -1e30f; int bi = 0;
#pragma unroll
        for (int e = 0; e < NE; e++) {
            lg[e] = gred[row][e][0] + gred[row][e][1] + gred[row][e][2] + gred[row][e][3] + gb[e];
            if (lg[e] > best) { best = lg[e]; bi = e; }
        }
        float ssum = 0.f;
#pragma unroll
        for (int e = 0; e < NE; e++) ssum += __expf(lg[e] - best);
        top_idx[m0 + row] = bi;
        top_w[m0 + row] = 1.f / ssum;
    }
}

// ---------------------------------------------------------------------------
// Fused MoE fc2 + top_w scale + residual + LayerNorm2 (scatter by token).
// Block = 16 expert-sorted rows x 256 cols, K=1024. grid (tiles, NE).
// ---------------------------------------------------------------------------
__global__ __launch_bounds__(256) void fc2_ln(
    const ushort_t* __restrict__ ehb, const ushort_t* __restrict__ Wb,
    const float* __restrict__ b2, const int* __restrict__ counts,
    const int* __restrict__ perm, const float* __restrict__ topw,
    float* __restrict__ h, ushort_t* __restrict__ hb,
    const float* __restrict__ g, const float* __restrict__ b)
{
    __shared__ ushort_t As[16 * 64];     // 2 KB
    __shared__ ushort_t Bs[256 * 64];    // 32 KB
    __shared__ float lsum[16][4], lsq[16][4];
    const int e = blockIdx.y;
    const int cnt = counts[e * CSTRIDE];
    const int m0 = blockIdx.x * 16;
    if (m0 >= cnt) return;
    int off = 0;
    for (int i = 0; i < e; i++) off += counts[i * CSTRIDE];
    const ushort_t* Wp = Wb + (size_t)e * 256 * 1024;
    const float* bp = b2 + e * 256;
    const int tid = threadIdx.x;
    const int lane = tid & 63, wave = tid >> 6;
    const int r8 = lane >> 3, p = lane & 7;
    const int kswz = ((p ^ r8) << 3);
    const int quad = lane >> 4, fr = lane & 15;
    const int wn = wave * 64;
    size_t arow = 0;
    if (wave < 2) {
        const int gr = m0 + wave * 8 + r8;
        arow = (size_t)(off + ((gr < cnt) ? gr : m0));
    }
    floatx4 acc[4];
#pragma unroll
    for (int n = 0; n < 4; n++) acc[n] = (floatx4){0.f, 0.f, 0.f, 0.f};

    for (int k0 = 0; k0 < 1024; k0 += 64) {
        __syncthreads();
        if (wave < 2)
            GLD16(ehb + arow * 1024 + k0 + kswz, &As[(wave * 8) * 64]);
#pragma unroll
        for (int c = 0; c < 8; c++)
            GLD16(Wp + (size_t)(wn + c * 8 + r8) * 1024 + k0 + kswz,
                  &Bs[(wn + c * 8) * 64]);
        __syncthreads();
#pragma unroll
        for (int ks = 0; ks < 2; ks++) {
            const int sw = (((ks * 4 + quad) ^ (fr & 7)) << 3);
            short8 fa = *(const short8*)&As[fr * 64 + sw];
#pragma unroll
            for (int n = 0; n < 4; n++) {
                short8 fb = *(const short8*)&Bs[(wn + n * 16 + fr) * 64 + sw];
                acc[n] = __builtin_amdgcn_mfma_f32_16x16x32_bf16(fa, fb, acc[n], 0, 0, 0);
            }
        }
    }
    // ---- epilogue: scale + residual -> LN -> scatter write ----
    const int rbase = quad * 4;
    int tokr[4]; bool vld[4]; float twr[4];
#pragma unroll
    for (int r = 0; r < 4; r++) {
        const int grow = m0 + rbase + r;
        vld[r] = grow < cnt;
        tokr[r] = perm[off + (vld[r] ? grow : 0)];
        twr[r] = topw[tokr[r]];
    }
    float val[4][4];
#pragma unroll
    for (int n = 0; n < 4; n++) {
        const int col = wn + n * 16 + fr;
        const float bsv = bp[col];
#pragma unroll
        for (int r = 0; r < 4; r++)
            val[r][n] = vld[r]
                ? (acc[n][r] + bsv) * twr[r] + h[(size_t)tokr[r] * 256 + col]
                : 0.f;
    }
    float s[4], sq[4];
#pragma unroll
    for (int r = 0; r < 4; r++) {
        s[r]  = val[r][0] + val[r][1] + val[r][2] + val[r][3];
        sq[r] = val[r][0] * val[r][0] + val[r][1] * val[r][1]
              + val[r][2] * val[r][2] + val[r][3] * val[r][3];
    }
#pragma unroll
    for (int ox = 1; ox < 16; ox <<= 1)
#pragma unroll
        for (int r = 0; r < 4; r++) {
            s[r] += __shfl_xor(s[r], ox);
            sq[r] += __shfl_xor(sq[r], ox);
        }
    if (fr == 0)
#pragma unroll
        for (int r = 0; r < 4; r++) { lsum[rbase + r][wave] = s[r]; lsq[rbase + r][wave] = sq[r]; }
    __syncthreads();
#pragma unroll
    for (int r = 0; r < 4; r++) {
        if (!vld[r]) continue;
        const int row = rbase + r;
        const float m = (lsum[row][0] + lsum[row][1] + lsum[row][2] + lsum[row][3]) * (1.f / 256.f);
        float v2 = (lsq[row][0] + lsq[row][1] + lsq[row][2] + lsq[row][3]) * (1.f / 256.f) - m * m;
        const float rstd = rsqrtf(fmaxf(v2, 0.f) + 1e-5f);
#pragma unroll
        for (int n = 0; n < 4; n++) {
            const int col = wn + n * 16 + fr;
            const float o = (val[r][n] - m) * rstd * g[col] + b[col];
            const size_t idx = (size_t)tokr[r] * 256 + col;
            h[idx] = o;
            hb[idx] = bf16r(o);
        }
    }
}

// ---------------------------------------------------------------------------
// MFMA flash-style attention (verified round 3).
// ---------------------------------------------------------------------------
__global__ __launch_bounds__(256) void attn_kernel(
    const ushort_t* __restrict__ qkvb, const int* __restrict__ pad,
    ushort_t* __restrict__ ctxb)
{
    __shared__ ushort_t Kt[64 * 40];
    __shared__ ushort_t Vt[32 * 72];
    __shared__ ushort_t Ps[64 * 72];
    __shared__ float padf[512];
    const int tid = threadIdx.x;
    const int lane = tid & 63;
    const int wave = tid >> 6;
    const int quad = lane >> 4;
    const int l16  = lane & 15;
    const int bid = blockIdx.x;
    const int qt = bid & 7;
    const int hh = (bid >> 3) & 7;
    const int b = bid >> 6;
    const int q0 = wave * 16;

    padf[tid]       = (float)pad[b * SEQ + tid];
    padf[tid + 256] = (float)pad[b * SEQ + 256 + tid];

    short8 qfrag = *(const short8*)(qkvb +
        (size_t)(b * SEQ + qt * 64 + q0 + l16) * 768 + hh * 32 + quad * 8);

    const int skey = tid >> 2;
    const int schunk = (tid & 3) * 8;

    floatx4 o0 = {0.f,0.f,0.f,0.f}, o1 = {0.f,0.f,0.f,0.f};
    float lsumr[4] = {0.f, 0.f, 0.f, 0.f};
    const float scale = 0.17677669529663687f;

    for (int t = 0; t < 8; t++) {
        const int kbase = b * SEQ + t * 64;
        __syncthreads();
        uint4 kv = *(const uint4*)(qkvb + (size_t)(kbase + skey) * 768 + 256 + hh * 32 + schunk);
        *(uint4*)&Kt[skey * 40 + schunk] = kv;
        uint4 vv = *(const uint4*)(qkvb + (size_t)(kbase + skey) * 768 + 512 + hh * 32 + schunk);
        ushort_t vs[8]; *(uint4*)vs = vv;
#pragma unroll
        for (int j = 0; j < 8; j++) {
            const int d = schunk + j;
            Vt[d * 72 + (skey ^ ((d >> 3) << 3))] = vs[j];
        }
        __syncthreads();
        floatx4 sfr[4];
#pragma unroll
        for (int fn = 0; fn < 4; fn++) {
            short8 kf = *(const short8*)&Kt[(fn * 16 + l16) * 40 + quad * 8];
            sfr[fn] = __builtin_amdgcn_mfma_f32_16x16x32_bf16(
                qfrag, kf, (floatx4){0.f,0.f,0.f,0.f}, 0, 0, 0);
        }
#pragma unroll
        for (int fn = 0; fn < 4; fn++) {
            const int keyl = fn * 16 + l16;
            const float pv = padf[t * 64 + keyl];
#pragma unroll
            for (int r = 0; r < 4; r++) {
                float pr = (pv != 0.f) ? 0.f : __expf(sfr[fn][r] * scale);
                ushort_t pb = bf16r(pr);
                lsumr[r] += __uint_as_float(((unsigned)pb) << 16);
                Ps[(q0 + quad * 4 + r) * 72 + keyl] = pb;
            }
        }
#pragma unroll
        for (int kc = 0; kc < 2; kc++) {
            short8 pf = *(const short8*)&Ps[(q0 + l16) * 72 + kc * 32 + quad * 8];
            {
                const int d = l16;
                short8 vf = *(const short8*)&Vt[d * 72 + ((kc * 32 + quad * 8) ^ ((d >> 3) << 3))];
                o0 = __builtin_amdgcn_mfma_f32_16x16x32_bf16(pf, vf, o0, 0, 0, 0);
            }
            {
                const int d = 16 + l16;
                short8 vf = *(const short8*)&Vt[d * 72 + ((kc * 32 + quad * 8) ^ ((d >> 3) << 3))];
                o1 = __builtin_amdgcn_mfma_f32_16x16x32_bf16(pf, vf, o1, 0, 0, 0);
            }
        }
    }
#pragma unroll
    for (int r = 0; r < 4; r++) {
        float v = lsumr[r];
        v += __shfl_xor(v, 1); v += __shfl_xor(v, 2);
        v += __shfl_xor(v, 4); v += __shfl_xor(v, 8);
        lsumr[r] = 1.f / v;
    }
    const int nq = b * SEQ + qt * 64 + q0 + quad * 4;
#pragma unroll
    for (int r = 0; r < 4; r++) {
        ushort_t* outp = ctxb + (size_t)(nq + r) * 256 + hh * 32;
        outp[l16]      = bf16r(o0[r] * lsumr[r]);
        outp[16 + l16] = bf16r(o1[r] * lsumr[r]);
    }
}

// ---------------------------------------------------------------------------
__global__ __launch_bounds__(256) void bucket_kernel(
    const int* __restrict__ top_idx, int* __restrict__ pos,
    int* __restrict__ counts)
{
    __shared__ int hist[NE];
    __shared__ int base[NE];
    __shared__ int lpos[256];
    const int n = blockIdx.x * 256 + threadIdx.x;
    if (threadIdx.x < NE) hist[threadIdx.x] = 0;
    __syncthreads();
    const int e = top_idx[n];
    lpos[threadIdx.x] = atomicAdd(&hist[e], 1);
    __syncthreads();
    if (threadIdx.x < NE)
        base[threadIdx.x] = atomicAdd(&counts[threadIdx.x * CSTRIDE], hist[threadIdx.x]);
    __syncthreads();
    pos[n] = base[e] + lpos[threadIdx.x];
}

__global__ __launch_bounds__(256) void scatter_perm(
    const int* __restrict__ top_idx, const int* __restrict__ pos,
    const int* __restrict__ counts, int* __restrict__ perm)
{
    __shared__ int offs_s[NE];
    if (threadIdx.x < NE) {
        int a = 0;
        for (int i = 0; i < (int)threadIdx.x; i++) a += counts[i * CSTRIDE];
        offs_s[threadIdx.x] = a;
    }
    __syncthreads();
    const int n = blockIdx.x * 256 + threadIdx.x;
    if (n < NTOK) perm[offs_s[top_idx[n]] + pos[n]] = n;
}

// ---------------------------------------------------------------------------
__global__ __launch_bounds__(256) void pool1(
    const float* __restrict__ h, const int* __restrict__ pad,
    float* __restrict__ pooled, float* __restrict__ cntb)
{
    const int b = blockIdx.x, c = blockIdx.y, d = threadIdx.x;
    float s = 0.0f; int cnt = 0;
    for (int i = 0; i < 32; i++) {
        const int idx = b * SEQ + c * 32 + i;
        if (!pad[idx]) { s += h[(size_t)idx * D_MODEL + d]; cnt++; }
    }
    atomicAdd(&pooled[b * D_MODEL + d], s);
    if (d == 0) atomicAdd(&cntb[b], (float)cnt);
}

__global__ __launch_bounds__(128) void cls_kernel(
    const float* __restrict__ pooled, const float* __restrict__ cntb,
    const float* __restrict__ fc1w, const float* __restrict__ fc1b,
    const float* __restrict__ fc2w, const float* __restrict__ fc2b,
    float* __restrict__ out)
{
    __shared__ float zs[128];
    const int b = blockIdx.x;
    const int j = threadIdx.x;
    const float invc = 1.0f / fmaxf(cntb[b], 1.0f);
    float s = 0.0f;
    for (int d = 0; d < D_MODEL; d++) s += pooled[b * D_MODEL + d] * fc1w[j * D_MODEL + d];
    zs[j] = fmaxf(s * invc + fc1b[j], 0.0f);
    __syncthreads();
    if (j < 2) {
        float o = fc2b[j];
        for (int i = 0; i < 128; i++) o += zs[i] * fc2w[j * 128 + i];
        out[b * 2 + j] = o;
    }
}

// ---------------------------------------------------------------------------
extern "C" void kernel_launch(void* const* d_in, const int* in_sizes, int n_in,
                              void* d_out, int out_size, void* d_ws, size_t ws_size,
                              hipStream_t stream)
{
    const int*   x          = (const int*)d_in[0];
    const float* emb        = (const float*)d_in[1];
    const float* in_proj_w  = (const float*)d_in[2];
    const float* in_proj_b  = (const float*)d_in[3];
    const float* out_proj_w = (const float*)d_in[4];
    const float* out_proj_b = (const float*)d_in[5];
    const float* ln1_g      = (const float*)d_in[6];
    const float* ln1_b      = (const float*)d_in[7];
    const float* ln2_g      = (const float*)d_in[8];
    const float* ln2_b      = (const float*)d_in[9];
    const float* gate_w     = (const float*)d_in[10];
    const float* gate_b     = (const float*)d_in[11];
    const float* w1         = (const float*)d_in[12];
    const float* b1         = (const float*)d_in[13];
    const float* w2         = (const float*)d_in[14];
    const float* b2         = (const float*)d_in[15];
    const float* fc1_w      = (const float*)d_in[16];
    const float* fc1_b      = (const float*)d_in[17];
    const float* fc2_w      = (const float*)d_in[18];
    const float* fc2_b      = (const float*)d_in[19];
    float* out = (float*)d_out;

    float* ws = (float*)d_ws;
    float*    h      = ws;                          // 2,097,152
    ushort_t* qkvb   = (ushort_t*)(ws + 4194304);   // 8192*768 bf16
    ushort_t* ctxb   = (ushort_t*)(ws + 7340032);   // 8192*256 bf16
    ushort_t* ehb    = (ushort_t*)(ws + 4194304);   // aliases qkvb+ctxb
    ushort_t* hb     = (ushort_t*)(ws + 8388608);   // 8192*256 bf16
    float*    top_w  = ws + 9437184;                // 8192
    float*    pooled = ws + 9445376;
    float*    cntb   = ws + 9449472;
    int*      counts = (int*)(ws + 9449488);        // 2 * NE * CSTRIDE
    int* ipart   = (int*)(ws + 9450000);
    int* pad     = ipart;
    int* top_idx = ipart + 8192;
    int* pos     = ipart + 16384;
    int* perm    = ipart + 24576;
    ushort_t* wball = (ushort_t*)(ws + 9482768);

    wconv_all<<<8704, 256, 0, stream>>>(in_proj_w, out_proj_w, w1, w2, wball);
    embed_kernel<<<NTOK, 256, 0, stream>>>(x, emb, h, hb, pad);
    hipMemsetAsync(pooled, 0, (4096 + 16 + 2 * NE * CSTRIDE) * sizeof(float), stream);

    for (int l = 0; l < 2; l++) {
        const ushort_t* inb_l  = wball + (size_t)l * 196608;
        const ushort_t* outb_l = wball + 393216 + (size_t)l * 65536;
        const ushort_t* w1b_l  = wball + 524288 + (size_t)l * 2097152;
        const ushort_t* w2b_l  = wball + 4718592 + (size_t)l * 2097152;
        int* counts_l = counts + l * NE * CSTRIDE;

        // --- qkv projection ---
        gemm_gl64<<<dim3(768 / 64, NTOK / 64, 1), 256, 0, stream>>>(
            hb, inb_l, in_proj_b + l * 768, qkvb, NTOK, 768, 256,
            nullptr, nullptr, nullptr, GF_OUTBF16);
        // --- attention ---
        attn_kernel<<<NB * NH * (SEQ / 64), 256, 0, stream>>>(qkvb, pad, ctxb);
        // --- out_proj + residual + LN1 + gate (fused) ---
        oproj_ln<<<NTOK / 16, 256, 0, stream>>>(
            ctxb, outb_l, out_proj_b + l * 256, h, hb,
            ln1_g + l * 256, ln1_b + l * 256,
            gate_w + l * NE * 256, gate_b + l * NE, top_idx, top_w);
        // --- routing ---
        bucket_kernel<<<NTOK / 256, 256, 0, stream>>>(top_idx, pos, counts_l);
        scatter_perm<<<NTOK / 256, 256, 0, stream>>>(top_idx, pos, counts_l, perm);
        // --- MoE fc1 (routed expert only) ---
        gemm_gl64<<<dim3(EHID / 64, NTOK / 64, NE), 256, 0, stream>>>(
            hb, w1b_l, b1 + l * NE * EHID, ehb, 0, EHID, 256,
            counts_l, perm, nullptr, GF_GATHER | GF_RELU | GF_OUTBF16);
        // --- MoE fc2 + scale + residual + LN2 (fused) ---
        fc2_ln<<<dim3(NTOK / 16, NE), 256, 0, stream>>>(
            ehb, w2b_l, b2 + l * NE * 256, counts_l, perm, top_w,
            h, hb, ln2_g + l * 256, ln2_b + l * 256);
    }

    pool1<<<dim3(NB, 16), 256, 0, stream>>>(h, pad, pooled, cntb);
    cls_kernel<<<NB, 128, 0, stream>>>(pooled, cntb, fc1_w, fc1_b, fc2_w, fc2_b, out);
}